// Round 18
// baseline (327.043 us; speedup 1.0000x reference)
//
#include <hip/hip_runtime.h>
#include <hip/hip_bf16.h>

// Performer (ORF linear attention) + out-proj + residual + LayerNorm.
// Round 18: QKV GEMM reads A as fp32 directly (fused cast) with a DEPTH-2
// register pipeline: LOADA(tile T+2) issued at iter T, WRITEA(tile T+1)
// from regs loaded at iter T-1 -> full-iteration HBM latency cover.
// One barrier per K-step; B via gload_lds dbuf with counted vmcnt.
// Everything else identical to round 17 (best known, 287.9 us).

typedef float f4 __attribute__((ext_vector_type(4)));
typedef __attribute__((ext_vector_type(8))) short bf16x8;
typedef __attribute__((ext_vector_type(4))) float f32x4;
typedef unsigned short u16x4 __attribute__((ext_vector_type(4)));
typedef unsigned short u16x8 __attribute__((ext_vector_type(8)));

#define B_  4
#define L_  2048
#define H_  16
#define D_  64
#define DM_ 1024
#define R_  256
#define C_  64
#define NC_ (L_ / C_)
#define M_  (B_ * L_)
#define M2_ (M_ * H_)

static __device__ __forceinline__ unsigned short f2bu(float x) {
    __hip_bfloat16 h = __float2bfloat16(x);
    return *(unsigned short*)&h;
}
static __device__ __forceinline__ float bu2f(unsigned short u) {
    union { unsigned int i; float f; } c; c.i = ((unsigned int)u) << 16; return c.f;
}

typedef __attribute__((address_space(3))) void lds_void_t;
typedef __attribute__((address_space(1))) const void gvoid_t;
static __device__ __forceinline__ void gload16(const void* g, void* l) {
    __builtin_amdgcn_global_load_lds((gvoid_t*)g, (lds_void_t*)l, 16, 0, 0);
}

// ---------------------------------------------------------------------------
// fp32 -> bf16 casts (weights / omega / wo only — big inputs now fused)
// ---------------------------------------------------------------------------
__launch_bounds__(256)
__global__ void cvt_bf16(const float* __restrict__ in, unsigned short* __restrict__ out, int n4) {
    int i = blockIdx.x * 256 + threadIdx.x;
    if (i < n4) {
        f4 v = *(const f4*)&in[(size_t)i * 4];
        ushort4 o;
        o.x = f2bu(v[0]); o.y = f2bu(v[1]); o.z = f2bu(v[2]); o.w = f2bu(v[3]);
        *(ushort4*)&out[(size_t)i * 4] = o;
    }
}

__launch_bounds__(256)
__global__ void cvt_bf16_x4(const float* __restrict__ i0, const float* __restrict__ i1,
                            const float* __restrict__ i2, const float* __restrict__ i3,
                            unsigned short* __restrict__ o0, unsigned short* __restrict__ o1,
                            unsigned short* __restrict__ o2, unsigned short* __restrict__ o3,
                            int n4_abc, int n4_d) {
    const int z = blockIdx.z;
    const float* in = (z == 0) ? i0 : (z == 1) ? i1 : (z == 2) ? i2 : i3;
    unsigned short* out = (z == 0) ? o0 : (z == 1) ? o1 : (z == 2) ? o2 : o3;
    const int n4 = (z == 3) ? n4_d : n4_abc;
    int i = blockIdx.x * 256 + threadIdx.x;
    if (i < n4) {
        f4 v = *(const f4*)&in[(size_t)i * 4];
        ushort4 o;
        o.x = f2bu(v[0]); o.y = f2bu(v[1]); o.z = f2bu(v[2]); o.w = f2bu(v[3]);
        *(ushort4*)&out[(size_t)i * 4] = o;
    }
}

// ---------------------------------------------------------------------------
// Batched (z=0..2) C_z = A_z(fp32) @ B_z(bf16)^T, bf16 out, 128x128, BK=32.
// Depth-2 fused-cast pipeline (see header comment). XOR-swizzled LDS tiles.
// ---------------------------------------------------------------------------
__launch_bounds__(256)
__global__ void gemm_qkv(const float* __restrict__ A0, const float* __restrict__ A1,
                         const float* __restrict__ A2,
                         const unsigned short* __restrict__ B0, const unsigned short* __restrict__ B1,
                         const unsigned short* __restrict__ B2,
                         unsigned short* __restrict__ C0, unsigned short* __restrict__ C1,
                         unsigned short* __restrict__ C2,
                         int M, int N, int K) {
    __shared__ unsigned short Asl[2][128 * 32];   // 2 x 8 KB
    __shared__ unsigned short Bsl[2][128 * 32];   // 2 x 8 KB
    const int z = blockIdx.z;
    const float* A = (z == 0) ? A0 : (z == 1) ? A1 : A2;
    const unsigned short* Bw = (z == 0) ? B0 : (z == 1) ? B1 : B2;
    unsigned short*       Cb = (z == 0) ? C0 : (z == 1) ? C1 : C2;
    const int t = threadIdx.x;
    const int lane = t & 63, w = t >> 6;
    const int wr = w >> 1, wc = w & 1;
    const int nwg = gridDim.x * gridDim.y;
    const int bid = blockIdx.y * gridDim.x + blockIdx.x;
    const int cpx = nwg >> 3;
    const int swz = (bid & 7) * cpx + (bid >> 3);
    const int row0 = (swz / gridDim.x) * 128, col0 = (swz % gridDim.x) * 128;
    const int sr0 = t >> 2;
    const int ssw = (((t & 3) ^ ((t >> 3) & 3)) * 8);   // pre-swizzled source elem offset
    const int lg = lane >> 4, lr = lane & 15;
    const int aslot = (lg ^ ((lr >> 1) & 3)) * 8;       // swizzled read slot

    // two named fp32 register sets (depth-2): set0 = even tiles, set1 = odd
    f4 s0a, s0b, s0c, s0d;
    f4 s1a, s1b, s1c, s1d;

#define LOADA0(kkk) do { \
        s0a = *(const f4*)&A[(size_t)(row0 + sr0)      * K + (kkk) + ssw]; \
        s0b = *(const f4*)&A[(size_t)(row0 + sr0)      * K + (kkk) + ssw + 4]; \
        s0c = *(const f4*)&A[(size_t)(row0 + sr0 + 64) * K + (kkk) + ssw]; \
        s0d = *(const f4*)&A[(size_t)(row0 + sr0 + 64) * K + (kkk) + ssw + 4]; \
    } while (0)
#define LOADA1(kkk) do { \
        s1a = *(const f4*)&A[(size_t)(row0 + sr0)      * K + (kkk) + ssw]; \
        s1b = *(const f4*)&A[(size_t)(row0 + sr0)      * K + (kkk) + ssw + 4]; \
        s1c = *(const f4*)&A[(size_t)(row0 + sr0 + 64) * K + (kkk) + ssw]; \
        s1d = *(const f4*)&A[(size_t)(row0 + sr0 + 64) * K + (kkk) + ssw + 4]; \
    } while (0)
#define WRITEA0(buf) do { \
        u16x8 w0 = { f2bu(s0a[0]), f2bu(s0a[1]), f2bu(s0a[2]), f2bu(s0a[3]), \
                     f2bu(s0b[0]), f2bu(s0b[1]), f2bu(s0b[2]), f2bu(s0b[3]) }; \
        u16x8 w1 = { f2bu(s0c[0]), f2bu(s0c[1]), f2bu(s0c[2]), f2bu(s0c[3]), \
                     f2bu(s0d[0]), f2bu(s0d[1]), f2bu(s0d[2]), f2bu(s0d[3]) }; \
        *(u16x8*)&Asl[buf][t * 8] = w0; \
        *(u16x8*)&Asl[buf][(t + 256) * 8] = w1; \
    } while (0)
#define WRITEA1(buf) do { \
        u16x8 w0 = { f2bu(s1a[0]), f2bu(s1a[1]), f2bu(s1a[2]), f2bu(s1a[3]), \
                     f2bu(s1b[0]), f2bu(s1b[1]), f2bu(s1b[2]), f2bu(s1b[3]) }; \
        u16x8 w1 = { f2bu(s1c[0]), f2bu(s1c[1]), f2bu(s1c[2]), f2bu(s1c[3]), \
                     f2bu(s1d[0]), f2bu(s1d[1]), f2bu(s1d[2]), f2bu(s1d[3]) }; \
        *(u16x8*)&Asl[buf][t * 8] = w0; \
        *(u16x8*)&Asl[buf][(t + 256) * 8] = w1; \
    } while (0)
#define STAGEB(buf, kkk) do { \
        gload16(&Bw[(size_t)(col0 + sr0)      * K + (kkk) + ssw], &Bsl[buf][t * 8]); \
        gload16(&Bw[(size_t)(col0 + sr0 + 64) * K + (kkk) + ssw], &Bsl[buf][(t + 256) * 8]); \
    } while (0)
#define COMPUTE(buf) do { \
        bf16x8 af[4], bfr[4]; \
        _Pragma("unroll") \
        for (int m = 0; m < 4; ++m) \
            af[m] = *(const bf16x8*)&Asl[buf][(wr * 64 + m * 16 + lr) * 32 + aslot]; \
        _Pragma("unroll") \
        for (int n = 0; n < 4; ++n) \
            bfr[n] = *(const bf16x8*)&Bsl[buf][(wc * 64 + n * 16 + lr) * 32 + aslot]; \
        __builtin_amdgcn_s_setprio(1); \
        _Pragma("unroll") \
        for (int m = 0; m < 4; ++m) \
            _Pragma("unroll") \
            for (int n = 0; n < 4; ++n) \
                acc[m][n] = __builtin_amdgcn_mfma_f32_16x16x32_bf16(af[m], bfr[n], acc[m][n], 0, 0, 0); \
        __builtin_amdgcn_s_setprio(0); \
    } while (0)

    f32x4 acc[4][4] = {};
    const int NT = K >> 5;                 // 32 tiles
    // prologue: stage B(tile0); load A tiles 0 and 1; write A tile0.
    STAGEB(0, 0);
    LOADA0(0);
    LOADA1(32);
    WRITEA0(0);                            // compiler waits set0 (B2 drained too)
    asm volatile("s_waitcnt lgkmcnt(0)" ::: "memory");
    __builtin_amdgcn_sched_barrier(0);
    __builtin_amdgcn_s_barrier();

    for (int T = 0; T < NT; T += 2) {
        // ---- even tile T: compute buf0 ----
        {
            const int hasN = 1;                       // T+1 <= NT-1 always (NT even)
            const int has2 = (T + 2 < NT);
            STAGEB(1, (T + 1) * 32);
            if (has2) LOADA0((T + 2) * 32);
            WRITEA1(1);                               // tile T+1 A, loaded one iter ago
            COMPUTE(0);
            if (has2) { asm volatile("s_waitcnt vmcnt(4)" ::: "memory"); }
            else      { asm volatile("s_waitcnt vmcnt(0)" ::: "memory"); }
            __builtin_amdgcn_sched_barrier(0);
            asm volatile("s_waitcnt lgkmcnt(0)" ::: "memory");
            __builtin_amdgcn_s_barrier();
            (void)hasN;
        }
        // ---- odd tile T+1: compute buf1 ----
        {
            const int has2 = (T + 2 < NT);
            const int has3 = (T + 3 < NT);
            if (has2) STAGEB(0, (T + 2) * 32);
            if (has3) LOADA1((T + 3) * 32);
            if (has2) WRITEA0(0);                     // tile T+2 A, loaded one iter ago
            COMPUTE(1);
            if (has2) {
                if (has3) { asm volatile("s_waitcnt vmcnt(4)" ::: "memory"); }
                else      { asm volatile("s_waitcnt vmcnt(0)" ::: "memory"); }
                __builtin_amdgcn_sched_barrier(0);
                asm volatile("s_waitcnt lgkmcnt(0)" ::: "memory");
                __builtin_amdgcn_s_barrier();
            }
        }
    }
#undef LOADA0
#undef LOADA1
#undef WRITEA0
#undef WRITEA1
#undef STAGEB
#undef COMPUTE
#pragma unroll
    for (int m = 0; m < 4; ++m)
#pragma unroll
        for (int n = 0; n < 4; ++n)
#pragma unroll
            for (int i = 0; i < 4; ++i) {
                int r  = row0 + wr * 64 + m * 16 + lg * 4 + i;
                int cc = col0 + wc * 64 + n * 16 + lr;
                Cb[(size_t)r * N + cc] = f2bu(acc[m][n][i]);
            }
}

// ---------------------------------------------------------------------------
// Out-proj GEMM: C = A @ B^T + fp32 resid, fp32 out. BM=64, BN=128, BK=32,
// 3-deep ring, counted vmcnt (3 loads/stage -> vmcnt 6/3/0). 1024 blocks.
// ---------------------------------------------------------------------------
__launch_bounds__(256)
__global__ void gemm_out(const unsigned short* __restrict__ A,
                         const unsigned short* __restrict__ Bw,
                         const float* __restrict__ resid,
                         float* __restrict__ Cf,
                         int M, int N, int K) {
    __shared__ unsigned short Asl[3][64 * 32];    // 3 x 4 KB
    __shared__ unsigned short Bsl[3][128 * 32];   // 3 x 8 KB
    const int t = threadIdx.x;
    const int lane = t & 63, w = t >> 6;
    const int nwg = gridDim.x * gridDim.y;
    const int bid = blockIdx.y * gridDim.x + blockIdx.x;
    const int cpx = nwg >> 3;
    const int swz = (bid & 7) * cpx + (bid >> 3);
    const int row0 = (swz / gridDim.x) * 64, col0 = (swz % gridDim.x) * 128;
    const int sr0 = t >> 2;
    const int ssw = (((t & 3) ^ ((t >> 3) & 3)) * 8);
    const int lg = lane >> 4, lr = lane & 15;
    const int aslot = (lg ^ ((lr >> 1) & 3)) * 8;

#define STAGE_O(buf, kkk) do { \
        gload16(&A [(size_t)(row0 + sr0)      * K + (kkk) + ssw], &Asl[buf][t * 8]); \
        gload16(&Bw[(size_t)(col0 + sr0)      * K + (kkk) + ssw], &Bsl[buf][t * 8]); \
        gload16(&Bw[(size_t)(col0 + sr0 + 64) * K + (kkk) + ssw], &Bsl[buf][(t + 256) * 8]); \
    } while (0)
#define COMPUTE_O(buf) do { \
        bf16x8 af[4], bfr[2]; \
        _Pragma("unroll") \
        for (int m = 0; m < 4; ++m) \
            af[m] = *(const bf16x8*)&Asl[buf][(m * 16 + lr) * 32 + aslot]; \
        _Pragma("unroll") \
        for (int n = 0; n < 2; ++n) \
            bfr[n] = *(const bf16x8*)&Bsl[buf][(w * 32 + n * 16 + lr) * 32 + aslot]; \
        _Pragma("unroll") \
        for (int m = 0; m < 4; ++m) \
            _Pragma("unroll") \
            for (int n = 0; n < 2; ++n) \
                acc[m][n] = __builtin_amdgcn_mfma_f32_16x16x32_bf16(af[m], bfr[n], acc[m][n], 0, 0, 0); \
    } while (0)

    f32x4 acc[4][2] = {};
    STAGE_O(0, 0);
    STAGE_O(1, 32);
    int cur = 0;
    for (int kk = 0; kk + 64 < K; kk += 32) {
        int nx = cur + 2; if (nx >= 3) nx -= 3;
        STAGE_O(nx, kk + 64);
        asm volatile("s_waitcnt vmcnt(6)" ::: "memory");
        __builtin_amdgcn_sched_barrier(0);
        __builtin_amdgcn_s_barrier();
        COMPUTE_O(cur);
        __builtin_amdgcn_s_barrier();
        cur = (cur == 2) ? 0 : cur + 1;
    }
    asm volatile("s_waitcnt vmcnt(3)" ::: "memory");
    __builtin_amdgcn_sched_barrier(0);
    __builtin_amdgcn_s_barrier();
    COMPUTE_O(cur);
    __builtin_amdgcn_s_barrier();
    cur = (cur == 2) ? 0 : cur + 1;
    asm volatile("s_waitcnt vmcnt(0)" ::: "memory");
    __builtin_amdgcn_sched_barrier(0);
    __builtin_amdgcn_s_barrier();
    COMPUTE_O(cur);
#undef STAGE_O
#undef COMPUTE_O
#pragma unroll
    for (int m = 0; m < 4; ++m)
#pragma unroll
        for (int n = 0; n < 2; ++n)
#pragma unroll
            for (int i = 0; i < 4; ++i) {
                int r  = row0 + m * 16 + lg * 4 + i;
                int cc = col0 + w * 32 + n * 16 + lr;
                size_t off = (size_t)r * N + cc;
                Cf[off] = acc[m][n][i] + resid[off];
            }
}

// ---------------------------------------------------------------------------
// Batched (z=0..1) feat: out[m,r] = bf16(sqrt(2/R)*cos(dot(X[m],om[r]) + b[r]))
// Xs and Pool(omega) XOR-swizzled; Pool reused as repack buffer.
// ---------------------------------------------------------------------------
#define RS_STRIDE 272
__launch_bounds__(256)
__global__ void feat_mfma_b2(const unsigned short* __restrict__ X0, const unsigned short* __restrict__ X1,
                             const unsigned short* __restrict__ om,
                             const float* __restrict__ bvec,
                             unsigned short* __restrict__ O0, unsigned short* __restrict__ O1) {
    __shared__ unsigned short Xs[2 * 64 * 32];        // 8 KB
    __shared__ unsigned short Pool[64 * RS_STRIDE];   // 34 KB: Os then Rs
    const int z = blockIdx.z;
    const unsigned short* X = z ? X1 : X0;
    unsigned short* out = z ? O1 : O0;
    const int t = threadIdx.x;
    const int lane = t & 63, w = t >> 6;
    const int lg = lane >> 4, lr = lane & 15;
    const int m0 = blockIdx.x * 64;
    const int aslot = (lg ^ ((lr >> 1) & 3)) * 8;

#pragma unroll
    for (int i = 0; i < 2; ++i) {
        int cch = i * 256 + t;
        int ks = cch >> 8, row = (cch >> 2) & 63;
        int sub = ((cch & 3) ^ ((cch >> 3) & 3)) * 8;   // pre-swizzled source
        gload16(&X[(size_t)(m0 + row) * 64 + ks * 32 + sub], &Xs[cch * 8]);
    }
#pragma unroll
    for (int i = 0; i < 8; ++i) {
        int cch = i * 256 + t;
        int ks = cch >> 10, r = (cch >> 2) & 255;
        int sub = ((cch & 3) ^ ((cch >> 3) & 3)) * 8;
        gload16(&om[(size_t)r * 64 + ks * 32 + sub], &Pool[cch * 8]);
    }
    __syncthreads();

    f32x4 acc[4][4] = {};
#pragma unroll
    for (int ks = 0; ks < 2; ++ks) {
        bf16x8 af[4], bfr[4];
#pragma unroll
        for (int m = 0; m < 4; ++m)
            af[m] = *(const bf16x8*)&Xs[ks * 2048 + (m * 16 + lr) * 32 + aslot];
#pragma unroll
        for (int n = 0; n < 4; ++n)
            bfr[n] = *(const bf16x8*)&Pool[ks * 8192 + (w * 64 + n * 16 + lr) * 32 + aslot];
#pragma unroll
        for (int m = 0; m < 4; ++m)
#pragma unroll
            for (int n = 0; n < 4; ++n)
                acc[m][n] = __builtin_amdgcn_mfma_f32_16x16x32_bf16(af[m], bfr[n], acc[m][n], 0, 0, 0);
    }
    __syncthreads();   // omega reads done; Pool becomes repack buffer

    const float scale = 0.08838834764831845f;  // sqrt(2/256)
#pragma unroll
    for (int n = 0; n < 4; ++n) {
        const int col = w * 64 + n * 16 + lr;
        const float bb = bvec[col];
#pragma unroll
        for (int m = 0; m < 4; ++m)
#pragma unroll
            for (int ii = 0; ii < 4; ++ii)
                Pool[(m * 16 + lg * 4 + ii) * RS_STRIDE + col] = f2bu(scale * __cosf(acc[m][n][ii] + bb));
    }
    __syncthreads();
#pragma unroll
    for (int i = 0; i < 8; ++i) {
        int cch = i * 256 + t;
        int row = cch >> 5, colc = (cch & 31) * 8;
        u16x8 vv = *(const u16x8*)&Pool[row * RS_STRIDE + colc];
        *(u16x8*)&out[(size_t)(m0 + row) * 256 + colc] = vv;
    }
}

// ---------------------------------------------------------------------------
// passA (MFMA): kvT[bh][c][d][r] = sum_l kp[l][r]*vb[l][d] (bf16), ksum[r].
// ---------------------------------------------------------------------------
__launch_bounds__(256)
__global__ void passA_mfma(const unsigned short* __restrict__ kp, const unsigned short* __restrict__ vb,
                           unsigned short* __restrict__ kvT, float* __restrict__ ksum) {
    __shared__ __align__(16) unsigned short KPt[256][72];  // [r][l]
    __shared__ __align__(16) unsigned short Vt[64][72];    // [d][l]
    const int c = blockIdx.x, h = blockIdx.y, bz = blockIdx.z;
    const int t = threadIdx.x;
    const int lane = t & 63, w = t >> 6;
    const int lg = lane >> 4, lr = lane & 15;
    const int l0 = c * C_;
    const int bh = bz * H_ + h;

    {   // stage KP^T
        const int l4 = (t & 15) * 4, rs = (t >> 4) * 16;
        u16x8 row[4][2];
#pragma unroll
        for (int i = 0; i < 4; ++i) {
            const unsigned short* src = &kp[((size_t)(bz * L_ + l0 + l4 + i) * H_ + h) * R_ + rs];
            row[i][0] = *(const u16x8*)src;
            row[i][1] = *(const u16x8*)(src + 8);
        }
#pragma unroll
        for (int q = 0; q < 16; ++q) {
            u16x4 pk = { row[0][q >> 3][q & 7], row[1][q >> 3][q & 7],
                         row[2][q >> 3][q & 7], row[3][q >> 3][q & 7] };
            *(u16x4*)&KPt[rs + q][l4] = pk;
        }
    }
    {   // stage V^T (bf16 pass-through)
        const int d4 = (t & 15) * 4, ls = (t >> 4) * 4;
        u16x4 x[4];
#pragma unroll
        for (int i = 0; i < 4; ++i)
            x[i] = *(const u16x4*)&vb[(size_t)(bz * L_ + l0 + ls + i) * DM_ + h * 64 + d4];
#pragma unroll
        for (int q = 0; q < 4; ++q) {
            u16x4 pk = { x[0][q], x[1][q], x[2][q], x[3][q] };
            *(u16x4*)&Vt[d4 + q][ls] = pk;
        }
    }
    __syncthreads();

    f32x4 acc[4][4] = {};
#pragma unroll
    for (int ks = 0; ks < 2; ++ks) {
        bf16x8 af[4], bfr[4];
#pragma unroll
        for (int m = 0; m < 4; ++m)
            af[m] = *(const bf16x8*)&KPt[64 * w + 16 * m + lr][ks * 32 + lg * 8];
#pragma unroll
        for (int n = 0; n < 4; ++n)
            bfr[n] = *(const bf16x8*)&Vt[16 * n + lr][ks * 32 + lg * 8];
#pragma unroll
        for (int m = 0; m < 4; ++m)
#pragma unroll
            for (int n = 0; n < 4; ++n)
                acc[m][n] = __builtin_amdgcn_mfma_f32_16x16x32_bf16(af[m], bfr[n], acc[m][n], 0, 0, 0);
    }
    size_t sbase = ((size_t)(bh * NC_ + c)) * 64 * R_;
#pragma unroll
    for (int n = 0; n < 4; ++n)
#pragma unroll
        for (int m = 0; m < 4; ++m) {
            int d = 16 * n + lr;
            int r = 64 * w + 16 * m + lg * 4;
            u16x4 pk = { f2bu(acc[m][n][0]), f2bu(acc[m][n][1]),
                         f2bu(acc[m][n][2]), f2bu(acc[m][n][3]) };
            *(u16x4*)&kvT[sbase + (size_t)d * R_ + r] = pk;
        }
    {
        float s = 0.f;
#pragma unroll
        for (int j = 0; j < 8; ++j) {
            u16x8 vv = *(const u16x8*)&KPt[t][j * 8];
#pragma unroll
            for (int q = 0; q < 8; ++q) s += bu2f(vv[q]);
        }
        ksum[((size_t)(bh * NC_ + c)) * R_ + t] = s;
    }
}

// ---------------------------------------------------------------------------
// passB: exclusive prefix over chunks of kvT ([bh][c][d][r]) and ksum.
// Vectorized: one u16x4 chain per thread. grid (16, H, B).
// ---------------------------------------------------------------------------
__launch_bounds__(256)
__global__ void passB_chain(unsigned short* __restrict__ kvT, float* __restrict__ ksum) {
    const int bx = blockIdx.x, h = blockIdx.y, bz = blockIdx.z;
    const int t = threadIdx.x;
    const int bh = bz * H_ + h;
    const int idx = bx * 256 + t;        // [0, 4096)
    const int d = idx >> 6;
    const int rg = (idx & 63) * 4;
    size_t base = ((size_t)bh * NC_ * 64 + d) * R_ + rg;
    const size_t cstride = (size_t)64 * R_;
    float run0 = 0.f, run1 = 0.f, run2 = 0.f, run3 = 0.f;
    for (int c = 0; c < NC_; ++c) {
        size_t ix = base + (size_t)c * cstride;
        u16x4 v = *(const u16x4*)&kvT[ix];
        u16x4 o = { f2bu(run0), f2bu(run1), f2bu(run2), f2bu(run3) };
        *(u16x4*)&kvT[ix] = o;
        run0 += bu2f(v[0]); run1 += bu2f(v[1]);
        run2 += bu2f(v[2]); run3 += bu2f(v[3]);
    }
    if (bx == 0) {
        float rz = 0.f;
        for (int c = 0; c < NC_; ++c) {
            size_t ix = ((size_t)bh * NC_ + c) * R_ + t;
            float tmp = ksum[ix];
            ksum[ix] = rz;
            rz += tmp;
        }
    }
}

// ---------------------------------------------------------------------------
// passC (MFMA): prologue async Sl prefetch (pre-swizzled source); scores with
// register-hoisted bk; Spref from LDS + zu fragments; AV+den; bf16 out.
// ---------------------------------------------------------------------------
__launch_bounds__(256)
__global__ void passC_mfma(const unsigned short* __restrict__ qp, const unsigned short* __restrict__ kp,
                           const unsigned short* __restrict__ vb, const unsigned short* __restrict__ kvT,
                           const float* __restrict__ zpref, unsigned short* __restrict__ attnb) {
    __shared__ __align__(16) unsigned short Sl[64 * 256];  // 32 KB, swizzled kvT tile
    __shared__ __align__(16) unsigned short Vt[80][72];    // [d][l], row64=ones
    __shared__ __align__(16) unsigned short As[64][72];    // masked scores

    const int c = blockIdx.x, h = blockIdx.y, bz = blockIdx.z;
    const int t = threadIdx.x;
    const int lane = t & 63, w = t >> 6;
    const int lg = lane >> 4, lr = lane & 15;
    const int l0 = c * C_;
    const int bh = bz * H_ + h;
    const size_t sbase = ((size_t)(bh * NC_ + c)) * 64 * R_;
    const size_t zbase = ((size_t)(bh * NC_ + c)) * R_;

#pragma unroll
    for (int i = 0; i < 8; ++i) {
        int idx = i * 256 + t;
        int row = idx >> 5, s = idx & 31;
        gload16(&kvT[sbase + (size_t)row * R_ + ((s ^ (row & 7)) << 3)], &Sl[idx * 8]);
    }

    {   // stage V^T (bf16 pass-through)
        const int d4 = (t & 15) * 4, ls = (t >> 4) * 4;
        u16x4 x[4];
#pragma unroll
        for (int i = 0; i < 4; ++i)
            x[i] = *(const u16x4*)&vb[(size_t)(bz * L_ + l0 + ls + i) * DM_ + h * 64 + d4];
#pragma unroll
        for (int q = 0; q < 4; ++q) {
            u16x4 pk = { x[0][q], x[1][q], x[2][q], x[3][q] };
            *(u16x4*)&Vt[d4 + q][ls] = pk;
        }
    }
    if (t < 16) {
        u16x4 ones = { 0x3F80, 0x3F80, 0x3F80, 0x3F80 };
        *(u16x4*)&Vt[64][t * 4] = ones;
    }

    const size_t qrow = ((size_t)(bz * L_ + l0 + 16 * w + lr) * H_ + h) * R_;
    bf16x8 aq[8];
#pragma unroll
    for (int ks = 0; ks < 8; ++ks) aq[ks] = *(const bf16x8*)&qp[qrow + ks * 32 + lg * 8];

    // ---- scores: two half-hoists of 16 bk fragments each ----
    f32x4 sacc[4] = {};
#pragma unroll
    for (int half = 0; half < 2; ++half) {
        bf16x8 bk[4][4];
#pragma unroll
        for (int k2 = 0; k2 < 4; ++k2)
#pragma unroll
            for (int n = 0; n < 4; ++n)
                bk[k2][n] = *(const bf16x8*)&kp[((size_t)(bz * L_ + l0 + 16 * n + lr) * H_ + h) * R_
                                                + (half * 4 + k2) * 32 + lg * 8];
        __builtin_amdgcn_s_setprio(1);
#pragma unroll
        for (int k2 = 0; k2 < 4; ++k2)
#pragma unroll
            for (int n = 0; n < 4; ++n)
                sacc[n] = __builtin_amdgcn_mfma_f32_16x16x32_bf16(aq[half * 4 + k2], bk[k2][n], sacc[n], 0, 0, 0);
        __builtin_amdgcn_s_setprio(0);
    }
#pragma unroll
    for (int n = 0; n < 4; ++n)
#pragma unroll
        for (int ii = 0; ii < 4; ++ii) {
            int i_loc = 16 * w + lg * 4 + ii;
            int j_loc = 16 * n + lr;
            As[i_loc][j_loc] = (j_loc <= i_loc) ? f2bu(sacc[n][ii]) : (unsigned short)0;
        }

    u16x8 zu[8];
#pragma unroll
    for (int ks = 0; ks < 8; ++ks) {
        f4 z0 = *(const f4*)&zpref[zbase + ks * 32 + lg * 8];
        f4 z1 = *(const f4*)&zpref[zbase + ks * 32 + lg * 8 + 4];
        zu[ks] = u16x8{ f2bu(z0[0]), f2bu(z0[1]), f2bu(z0[2]), f2bu(z0[3]),
                        f2bu(z1[0]), f2bu(z1[1]), f2bu(z1[2]), f2bu(z1[3]) };
    }
    __syncthreads();

    f32x4 oacc[4] = {};
    f32x4 dacc = {};
    __builtin_amdgcn_s_setprio(1);
#pragma unroll
    for (int ks = 0; ks < 8; ++ks) {
#pragma unroll
        for (int n = 0; n < 4; ++n) {
            int row = 16 * n + lr;
            int slot = (ks * 4 + lg) ^ (lr & 7);
            bf16x8 bs = *(const bf16x8*)&Sl[row * 256 + slot * 8];
            oacc[n] = __builtin_amdgcn_mfma_f32_16x16x32_bf16(aq[ks], bs, oacc[n], 0, 0, 0);
        }
        dacc = __builtin_amdgcn_mfma_f32_16x16x32_bf16(aq[ks], *(bf16x8*)&zu[ks], dacc, 0, 0, 0);
    }

    f32x4 racc = {};
#pragma unroll
    for (int ks = 0; ks < 2; ++ks) {
        bf16x8 aa = *(const bf16x8*)&As[16 * w + lr][ks * 32 + lg * 8];
#pragma unroll
        for (int n = 0; n < 4; ++n) {
            bf16x8 bv = *(const bf16x8*)&Vt[16 * n + lr][ks * 32 + lg * 8];
            oacc[n] = __builtin_amdgcn_mfma_f32_16x16x32_bf16(aa, bv, oacc[n], 0, 0, 0);
        }
        bf16x8 b4 = *(const bf16x8*)&Vt[64 + lr][ks * 32 + lg * 8];
        racc = __builtin_amdgcn_mfma_f32_16x16x32_bf16(aa, b4, racc, 0, 0, 0);
    }
    __builtin_amdgcn_s_setprio(0);

#pragma unroll
    for (int ii = 0; ii < 4; ++ii) {
        float rs_ = __shfl(racc[ii], lane & 48, 64);
        float den = rs_ + dacc[ii];
        float inv = 1.f / (fmaxf(den, 1e-6f) + 1e-6f);
#pragma unroll
        for (int n = 0; n < 4; ++n)
            attnb[(size_t)(bz * L_ + l0 + 16 * w + lg * 4 + ii) * DM_ + h * 64 + 16 * n + lr] =
                f2bu(oacc[n][ii] * inv);
    }
}

// ---------------------------------------------------------------------------
// In-place row LayerNorm over last dim (1024), eps=1e-5.
// ---------------------------------------------------------------------------
__launch_bounds__(256)
__global__ void ln_kernel(float* __restrict__ io, const float* __restrict__ gamma,
                          const float* __restrict__ beta) {
    __shared__ float wsum[4], wsum2[4];
    const int row = blockIdx.x;
    const int t = threadIdx.x;
    f4 x = *(const f4*)&io[(size_t)row * DM_ + t * 4];
    float s  = x[0] + x[1] + x[2] + x[3];
    float s2 = x[0]*x[0] + x[1]*x[1] + x[2]*x[2] + x[3]*x[3];
#pragma unroll
    for (int o = 32; o > 0; o >>= 1) {
        s  += __shfl_down(s, o);
        s2 += __shfl_down(s2, o);
    }
    if ((t & 63) == 0) { wsum[t >> 6] = s; wsum2[t >> 6] = s2; }
    __syncthreads();
    s  = wsum[0]  + wsum[1]  + wsum[2]  + wsum[3];
    s2 = wsum2[0] + wsum2[1] + wsum2[2] + wsum2[3];
    const float m = s * (1.f / DM_);
    const float var = s2 * (1.f / DM_) - m * m;
    const float rstd = rsqrtf(var + 1e-5f);
    f4 g  = *(const f4*)&gamma[t * 4];
    f4 bb = *(const f4*)&beta[t * 4];
    f4 o = (x - m) * rstd * g + bb;
    *(f4*)&io[(size_t)row * DM_ + t * 4] = o;
}

// ---------------------------------------------------------------------------
// Workspace (226 MB), staged aliasing (audited):
//  persistent: qp[0,64) kp[64,128) kvT[128,192) vb[192,208) attnb[208,224) ksum[224,226)
//  QKV phase: weights wq/wk/wv bf16 at [48,54) (qp slot, dead until feat)
//             outputs qx[128,144) kx[144,160) vb[192,208)
//  om_bf at [208,208.07) (attnb slot; dead before passC writes attnb)
//  feat: reads qx/kx+om, writes qp[0,64) + kp[64,128)
//  passA: writes kvT[128,192) ; wo_bf[64,66) after passC (kp dead)
// ---------------------------------------------------------------------------
extern "C" void kernel_launch(void* const* d_in, const int* in_sizes, int n_in,
                              void* d_out, int out_size, void* d_ws, size_t ws_size,
                              hipStream_t stream) {
    const float* pre_q = (const float*)d_in[0];
    const float* pre_k = (const float*)d_in[1];
    const float* pre_v = (const float*)d_in[2];
    const float* wq    = (const float*)d_in[3];
    const float* wk    = (const float*)d_in[4];
    const float* wv    = (const float*)d_in[5];
    const float* wo    = (const float*)d_in[6];
    const float* gamma = (const float*)d_in[7];
    const float* beta  = (const float*)d_in[8];
    const float* omega = (const float*)d_in[9];
    const float* bvec  = (const float*)d_in[10];

    const size_t NEED = 226ull << 20;
    if (ws_size < NEED) return;

    char* w = (char*)d_ws;
    unsigned short* qp    = (unsigned short*)(w);
    unsigned short* kp    = (unsigned short*)(w + (64ull << 20));
    unsigned short* kvT   = (unsigned short*)(w + (128ull << 20));
    unsigned short* vb    = (unsigned short*)(w + (192ull << 20));
    unsigned short* attnb = (unsigned short*)(w + (208ull << 20));
    float*          ksum  = (float*)(w + (224ull << 20));
    // transients
    unsigned short* wq_bf = (unsigned short*)(w + (48ull << 20));
    unsigned short* wk_bf = (unsigned short*)(w + (50ull << 20));
    unsigned short* wv_bf = (unsigned short*)(w + (52ull << 20));
    unsigned short* qx    = (unsigned short*)(w + (128ull << 20));
    unsigned short* kx    = (unsigned short*)(w + (144ull << 20));
    unsigned short* om_bf = (unsigned short*)(w + (208ull << 20));
    unsigned short* wo_bf = (unsigned short*)(w + (64ull << 20));
    float*          outb  = (float*)d_out;

    const int n4_w   = DM_ * DM_ / 4;
    const int n4_om  = R_ * D_ / 4;
    dim3 gg3(DM_ / 128, M_ / 128, 3);   // 1536 blocks
    dim3 ggo(DM_ / 128, M_ / 64);       // out-proj: 1024 blocks

    cvt_bf16_x4<<<dim3((n4_w + 255) / 256, 1, 4), 256, 0, stream>>>(
        wq, wk, wv, omega, wq_bf, wk_bf, wv_bf, om_bf, n4_w, n4_om);

    // fused-cast QKV GEMM: A read fp32 directly, depth-2 pipeline
    gemm_qkv<<<gg3, 256, 0, stream>>>(pre_q, pre_k, pre_v, wq_bf, wk_bf, wv_bf,
                                      qx, kx, vb, M_, DM_, DM_);
    feat_mfma_b2<<<dim3(M2_ / 64, 1, 2), 256, 0, stream>>>(qx, kx, om_bf, bvec, qp, kp);

    passA_mfma<<<dim3(NC_, H_, B_), 256, 0, stream>>>(kp, vb, kvT, ksum);
    passB_chain<<<dim3(16, H_, B_), 256, 0, stream>>>(kvT, ksum);
    passC_mfma<<<dim3(NC_, H_, B_), 256, 0, stream>>>(qp, kp, vb, kvT, ksum, attnb);

    cvt_bf16<<<(n4_w + 255) / 256, 256, 0, stream>>>(wo, wo_bf, n4_w);
    gemm_out<<<ggo, 256, 0, stream>>>(attnb, wo_bf, pre_q, outb, M_, DM_, DM_);
    ln_kernel<<<M_, 256, 0, stream>>>(outb, gamma, beta);
}

// Round 19
// 290.859 us; speedup vs baseline: 1.1244x; 1.1244x over previous
//
#include <hip/hip_runtime.h>
#include <hip/hip_bf16.h>

// Performer (ORF linear attention) + out-proj + residual + LayerNorm.
// Round 19: final revert to round-17 configuration (best measured, 287.9 us).
// 128x128 3-ring counted-vmcnt GEMMs, XOR-swizzled LDS (conflicts=0),
// separate batched input casts, MFMA feat/passA/passC, vectorized passB.

typedef float f4 __attribute__((ext_vector_type(4)));
typedef __attribute__((ext_vector_type(8))) short bf16x8;
typedef __attribute__((ext_vector_type(4))) float f32x4;
typedef unsigned short u16x4 __attribute__((ext_vector_type(4)));
typedef unsigned short u16x8 __attribute__((ext_vector_type(8)));

#define B_  4
#define L_  2048
#define H_  16
#define D_  64
#define DM_ 1024
#define R_  256
#define C_  64
#define NC_ (L_ / C_)
#define M_  (B_ * L_)
#define M2_ (M_ * H_)

static __device__ __forceinline__ unsigned short f2bu(float x) {
    __hip_bfloat16 h = __float2bfloat16(x);
    return *(unsigned short*)&h;
}
static __device__ __forceinline__ float bu2f(unsigned short u) {
    union { unsigned int i; float f; } c; c.i = ((unsigned int)u) << 16; return c.f;
}

typedef __attribute__((address_space(3))) void lds_void_t;
typedef __attribute__((address_space(1))) const void gvoid_t;
static __device__ __forceinline__ void gload16(const void* g, void* l) {
    __builtin_amdgcn_global_load_lds((gvoid_t*)g, (lds_void_t*)l, 16, 0, 0);
}

// ---------------------------------------------------------------------------
// fp32 -> bf16 casts: single, 3-way and 4-way batched variants
// ---------------------------------------------------------------------------
__launch_bounds__(256)
__global__ void cvt_bf16(const float* __restrict__ in, unsigned short* __restrict__ out, int n4) {
    int i = blockIdx.x * 256 + threadIdx.x;
    if (i < n4) {
        f4 v = *(const f4*)&in[(size_t)i * 4];
        ushort4 o;
        o.x = f2bu(v[0]); o.y = f2bu(v[1]); o.z = f2bu(v[2]); o.w = f2bu(v[3]);
        *(ushort4*)&out[(size_t)i * 4] = o;
    }
}

__launch_bounds__(256)
__global__ void cvt_bf16_x3(const float* __restrict__ i0, const float* __restrict__ i1,
                            const float* __restrict__ i2,
                            unsigned short* __restrict__ o0, unsigned short* __restrict__ o1,
                            unsigned short* __restrict__ o2, int n4) {
    const int z = blockIdx.z;
    const float* in = (z == 0) ? i0 : (z == 1) ? i1 : i2;
    unsigned short* out = (z == 0) ? o0 : (z == 1) ? o1 : o2;
    int i = blockIdx.x * 256 + threadIdx.x;
    if (i < n4) {
        f4 v = *(const f4*)&in[(size_t)i * 4];
        ushort4 o;
        o.x = f2bu(v[0]); o.y = f2bu(v[1]); o.z = f2bu(v[2]); o.w = f2bu(v[3]);
        *(ushort4*)&out[(size_t)i * 4] = o;
    }
}

__launch_bounds__(256)
__global__ void cvt_bf16_x4(const float* __restrict__ i0, const float* __restrict__ i1,
                            const float* __restrict__ i2, const float* __restrict__ i3,
                            unsigned short* __restrict__ o0, unsigned short* __restrict__ o1,
                            unsigned short* __restrict__ o2, unsigned short* __restrict__ o3,
                            int n4_abc, int n4_d) {
    const int z = blockIdx.z;
    const float* in = (z == 0) ? i0 : (z == 1) ? i1 : (z == 2) ? i2 : i3;
    unsigned short* out = (z == 0) ? o0 : (z == 1) ? o1 : (z == 2) ? o2 : o3;
    const int n4 = (z == 3) ? n4_d : n4_abc;
    int i = blockIdx.x * 256 + threadIdx.x;
    if (i < n4) {
        f4 v = *(const f4*)&in[(size_t)i * 4];
        ushort4 o;
        o.x = f2bu(v[0]); o.y = f2bu(v[1]); o.z = f2bu(v[2]); o.w = f2bu(v[3]);
        *(ushort4*)&out[(size_t)i * 4] = o;
    }
}

// ---------------------------------------------------------------------------
// Batched (z=0..2) C_z = A_z @ B_z^T, bf16 out, 128x128 tile, BK=32.
// 3-deep LDS ring, counted vmcnt (loads span barriers), XOR-swizzled tiles.
// ---------------------------------------------------------------------------
__launch_bounds__(256)
__global__ void gemm_mfma_b3(const unsigned short* __restrict__ A0, const unsigned short* __restrict__ A1,
                             const unsigned short* __restrict__ A2,
                             const unsigned short* __restrict__ B0, const unsigned short* __restrict__ B1,
                             const unsigned short* __restrict__ B2,
                             unsigned short* __restrict__ C0, unsigned short* __restrict__ C1,
                             unsigned short* __restrict__ C2,
                             int M, int N, int K) {
    __shared__ unsigned short Asl[3][128 * 32];   // 3 x 8 KB
    __shared__ unsigned short Bsl[3][128 * 32];   // 3 x 8 KB
    const int z = blockIdx.z;
    const unsigned short* A  = (z == 0) ? A0 : (z == 1) ? A1 : A2;
    const unsigned short* Bw = (z == 0) ? B0 : (z == 1) ? B1 : B2;
    unsigned short*       Cb = (z == 0) ? C0 : (z == 1) ? C1 : C2;
    const int t = threadIdx.x;
    const int lane = t & 63, w = t >> 6;
    const int wr = w >> 1, wc = w & 1;
    const int nwg = gridDim.x * gridDim.y;
    const int bid = blockIdx.y * gridDim.x + blockIdx.x;
    const int cpx = nwg >> 3;
    const int swz = (bid & 7) * cpx + (bid >> 3);
    const int row0 = (swz / gridDim.x) * 128, col0 = (swz % gridDim.x) * 128;
    const int sr0 = t >> 2;
    const int ssw = (((t & 3) ^ ((t >> 3) & 3)) * 8);   // pre-swizzled source chunk
    const int lg = lane >> 4, lr = lane & 15;
    const int aslot = (lg ^ ((lr >> 1) & 3)) * 8;       // swizzled read slot

#define STAGE_B3(buf, kkk) do { \
        gload16(&A [(size_t)(row0 + sr0)      * K + (kkk) + ssw], &Asl[buf][t * 8]); \
        gload16(&A [(size_t)(row0 + sr0 + 64) * K + (kkk) + ssw], &Asl[buf][(t + 256) * 8]); \
        gload16(&Bw[(size_t)(col0 + sr0)      * K + (kkk) + ssw], &Bsl[buf][t * 8]); \
        gload16(&Bw[(size_t)(col0 + sr0 + 64) * K + (kkk) + ssw], &Bsl[buf][(t + 256) * 8]); \
    } while (0)
#define COMPUTE_B3(buf) do { \
        bf16x8 af[4], bfr[4]; \
        _Pragma("unroll") \
        for (int m = 0; m < 4; ++m) \
            af[m] = *(const bf16x8*)&Asl[buf][(wr * 64 + m * 16 + lr) * 32 + aslot]; \
        _Pragma("unroll") \
        for (int n = 0; n < 4; ++n) \
            bfr[n] = *(const bf16x8*)&Bsl[buf][(wc * 64 + n * 16 + lr) * 32 + aslot]; \
        _Pragma("unroll") \
        for (int m = 0; m < 4; ++m) \
            _Pragma("unroll") \
            for (int n = 0; n < 4; ++n) \
                acc[m][n] = __builtin_amdgcn_mfma_f32_16x16x32_bf16(af[m], bfr[n], acc[m][n], 0, 0, 0); \
    } while (0)

    f32x4 acc[4][4] = {};
    STAGE_B3(0, 0);
    STAGE_B3(1, 32);
    int cur = 0;
    for (int kk = 0; kk + 64 < K; kk += 32) {
        int nx = cur + 2; if (nx >= 3) nx -= 3;
        STAGE_B3(nx, kk + 64);
        asm volatile("s_waitcnt vmcnt(8)" ::: "memory");
        __builtin_amdgcn_sched_barrier(0);
        __builtin_amdgcn_s_barrier();
        COMPUTE_B3(cur);
        __builtin_amdgcn_s_barrier();
        cur = (cur == 2) ? 0 : cur + 1;
    }
    asm volatile("s_waitcnt vmcnt(4)" ::: "memory");
    __builtin_amdgcn_sched_barrier(0);
    __builtin_amdgcn_s_barrier();
    COMPUTE_B3(cur);
    __builtin_amdgcn_s_barrier();
    cur = (cur == 2) ? 0 : cur + 1;
    asm volatile("s_waitcnt vmcnt(0)" ::: "memory");
    __builtin_amdgcn_sched_barrier(0);
    __builtin_amdgcn_s_barrier();
    COMPUTE_B3(cur);
#undef STAGE_B3
#undef COMPUTE_B3
#pragma unroll
    for (int m = 0; m < 4; ++m)
#pragma unroll
        for (int n = 0; n < 4; ++n)
#pragma unroll
            for (int i = 0; i < 4; ++i) {
                int r  = row0 + wr * 64 + m * 16 + lg * 4 + i;
                int cc = col0 + wc * 64 + n * 16 + lr;
                Cb[(size_t)r * N + cc] = f2bu(acc[m][n][i]);
            }
}

// ---------------------------------------------------------------------------
// Out-proj GEMM: C = A @ B^T + fp32 resid, fp32 out. BM=64, BN=128, BK=32,
// 3-deep ring, counted vmcnt (3 loads/stage -> vmcnt 6/3/0). 1024 blocks.
// ---------------------------------------------------------------------------
__launch_bounds__(256)
__global__ void gemm_out(const unsigned short* __restrict__ A,
                         const unsigned short* __restrict__ Bw,
                         const float* __restrict__ resid,
                         float* __restrict__ Cf,
                         int M, int N, int K) {
    __shared__ unsigned short Asl[3][64 * 32];    // 3 x 4 KB
    __shared__ unsigned short Bsl[3][128 * 32];   // 3 x 8 KB
    const int t = threadIdx.x;
    const int lane = t & 63, w = t >> 6;
    const int nwg = gridDim.x * gridDim.y;
    const int bid = blockIdx.y * gridDim.x + blockIdx.x;
    const int cpx = nwg >> 3;
    const int swz = (bid & 7) * cpx + (bid >> 3);
    const int row0 = (swz / gridDim.x) * 64, col0 = (swz % gridDim.x) * 128;
    const int sr0 = t >> 2;
    const int ssw = (((t & 3) ^ ((t >> 3) & 3)) * 8);
    const int lg = lane >> 4, lr = lane & 15;
    const int aslot = (lg ^ ((lr >> 1) & 3)) * 8;

#define STAGE_O(buf, kkk) do { \
        gload16(&A [(size_t)(row0 + sr0)      * K + (kkk) + ssw], &Asl[buf][t * 8]); \
        gload16(&Bw[(size_t)(col0 + sr0)      * K + (kkk) + ssw], &Bsl[buf][t * 8]); \
        gload16(&Bw[(size_t)(col0 + sr0 + 64) * K + (kkk) + ssw], &Bsl[buf][(t + 256) * 8]); \
    } while (0)
#define COMPUTE_O(buf) do { \
        bf16x8 af[4], bfr[2]; \
        _Pragma("unroll") \
        for (int m = 0; m < 4; ++m) \
            af[m] = *(const bf16x8*)&Asl[buf][(m * 16 + lr) * 32 + aslot]; \
        _Pragma("unroll") \
        for (int n = 0; n < 2; ++n) \
            bfr[n] = *(const bf16x8*)&Bsl[buf][(w * 32 + n * 16 + lr) * 32 + aslot]; \
        _Pragma("unroll") \
        for (int m = 0; m < 4; ++m) \
            _Pragma("unroll") \
            for (int n = 0; n < 2; ++n) \
                acc[m][n] = __builtin_amdgcn_mfma_f32_16x16x32_bf16(af[m], bfr[n], acc[m][n], 0, 0, 0); \
    } while (0)

    f32x4 acc[4][2] = {};
    STAGE_O(0, 0);
    STAGE_O(1, 32);
    int cur = 0;
    for (int kk = 0; kk + 64 < K; kk += 32) {
        int nx = cur + 2; if (nx >= 3) nx -= 3;
        STAGE_O(nx, kk + 64);
        asm volatile("s_waitcnt vmcnt(6)" ::: "memory");
        __builtin_amdgcn_sched_barrier(0);
        __builtin_amdgcn_s_barrier();
        COMPUTE_O(cur);
        __builtin_amdgcn_s_barrier();
        cur = (cur == 2) ? 0 : cur + 1;
    }
    asm volatile("s_waitcnt vmcnt(3)" ::: "memory");
    __builtin_amdgcn_sched_barrier(0);
    __builtin_amdgcn_s_barrier();
    COMPUTE_O(cur);
    __builtin_amdgcn_s_barrier();
    cur = (cur == 2) ? 0 : cur + 1;
    asm volatile("s_waitcnt vmcnt(0)" ::: "memory");
    __builtin_amdgcn_sched_barrier(0);
    __builtin_amdgcn_s_barrier();
    COMPUTE_O(cur);
#undef STAGE_O
#undef COMPUTE_O
#pragma unroll
    for (int m = 0; m < 4; ++m)
#pragma unroll
        for (int n = 0; n < 2; ++n)
#pragma unroll
            for (int i = 0; i < 4; ++i) {
                int r  = row0 + m * 16 + lg * 4 + i;
                int cc = col0 + w * 32 + n * 16 + lr;
                size_t off = (size_t)r * N + cc;
                Cf[off] = acc[m][n][i] + resid[off];
            }
}

// ---------------------------------------------------------------------------
// Batched (z=0..1) feat: out[m,r] = bf16(sqrt(2/R)*cos(dot(X[m],om[r]) + b[r]))
// Xs and Pool(omega) XOR-swizzled; Pool reused as repack buffer.
// ---------------------------------------------------------------------------
#define RS_STRIDE 272
__launch_bounds__(256)
__global__ void feat_mfma_b2(const unsigned short* __restrict__ X0, const unsigned short* __restrict__ X1,
                             const unsigned short* __restrict__ om,
                             const float* __restrict__ bvec,
                             unsigned short* __restrict__ O0, unsigned short* __restrict__ O1) {
    __shared__ unsigned short Xs[2 * 64 * 32];        // 8 KB
    __shared__ unsigned short Pool[64 * RS_STRIDE];   // 34 KB: Os then Rs
    const int z = blockIdx.z;
    const unsigned short* X = z ? X1 : X0;
    unsigned short* out = z ? O1 : O0;
    const int t = threadIdx.x;
    const int lane = t & 63, w = t >> 6;
    const int lg = lane >> 4, lr = lane & 15;
    const int m0 = blockIdx.x * 64;
    const int aslot = (lg ^ ((lr >> 1) & 3)) * 8;

#pragma unroll
    for (int i = 0; i < 2; ++i) {
        int cch = i * 256 + t;
        int ks = cch >> 8, row = (cch >> 2) & 63;
        int sub = ((cch & 3) ^ ((cch >> 3) & 3)) * 8;   // pre-swizzled source
        gload16(&X[(size_t)(m0 + row) * 64 + ks * 32 + sub], &Xs[cch * 8]);
    }
#pragma unroll
    for (int i = 0; i < 8; ++i) {
        int cch = i * 256 + t;
        int ks = cch >> 10, r = (cch >> 2) & 255;
        int sub = ((cch & 3) ^ ((cch >> 3) & 3)) * 8;
        gload16(&om[(size_t)r * 64 + ks * 32 + sub], &Pool[cch * 8]);
    }
    __syncthreads();

    f32x4 acc[4][4] = {};
#pragma unroll
    for (int ks = 0; ks < 2; ++ks) {
        bf16x8 af[4], bfr[4];
#pragma unroll
        for (int m = 0; m < 4; ++m)
            af[m] = *(const bf16x8*)&Xs[ks * 2048 + (m * 16 + lr) * 32 + aslot];
#pragma unroll
        for (int n = 0; n < 4; ++n)
            bfr[n] = *(const bf16x8*)&Pool[ks * 8192 + (w * 64 + n * 16 + lr) * 32 + aslot];
#pragma unroll
        for (int m = 0; m < 4; ++m)
#pragma unroll
            for (int n = 0; n < 4; ++n)
                acc[m][n] = __builtin_amdgcn_mfma_f32_16x16x32_bf16(af[m], bfr[n], acc[m][n], 0, 0, 0);
    }
    __syncthreads();   // omega reads done; Pool becomes repack buffer

    const float scale = 0.08838834764831845f;  // sqrt(2/256)
#pragma unroll
    for (int n = 0; n < 4; ++n) {
        const int col = w * 64 + n * 16 + lr;
        const float bb = bvec[col];
#pragma unroll
        for (int m = 0; m < 4; ++m)
#pragma unroll
            for (int ii = 0; ii < 4; ++ii)
                Pool[(m * 16 + lg * 4 + ii) * RS_STRIDE + col] = f2bu(scale * __cosf(acc[m][n][ii] + bb));
    }
    __syncthreads();
#pragma unroll
    for (int i = 0; i < 8; ++i) {
        int cch = i * 256 + t;
        int row = cch >> 5, colc = (cch & 31) * 8;
        u16x8 vv = *(const u16x8*)&Pool[row * RS_STRIDE + colc];
        *(u16x8*)&out[(size_t)(m0 + row) * 256 + colc] = vv;
    }
}

// ---------------------------------------------------------------------------
// passA (MFMA): kvT[bh][c][d][r] = sum_l kp[l][r]*vb[l][d] (bf16), ksum[r].
// ---------------------------------------------------------------------------
__launch_bounds__(256)
__global__ void passA_mfma(const unsigned short* __restrict__ kp, const unsigned short* __restrict__ vb,
                           unsigned short* __restrict__ kvT, float* __restrict__ ksum) {
    __shared__ __align__(16) unsigned short KPt[256][72];  // [r][l]
    __shared__ __align__(16) unsigned short Vt[64][72];    // [d][l]
    const int c = blockIdx.x, h = blockIdx.y, bz = blockIdx.z;
    const int t = threadIdx.x;
    const int lane = t & 63, w = t >> 6;
    const int lg = lane >> 4, lr = lane & 15;
    const int l0 = c * C_;
    const int bh = bz * H_ + h;

    {   // stage KP^T
        const int l4 = (t & 15) * 4, rs = (t >> 4) * 16;
        u16x8 row[4][2];
#pragma unroll
        for (int i = 0; i < 4; ++i) {
            const unsigned short* src = &kp[((size_t)(bz * L_ + l0 + l4 + i) * H_ + h) * R_ + rs];
            row[i][0] = *(const u16x8*)src;
            row[i][1] = *(const u16x8*)(src + 8);
        }
#pragma unroll
        for (int q = 0; q < 16; ++q) {
            u16x4 pk = { row[0][q >> 3][q & 7], row[1][q >> 3][q & 7],
                         row[2][q >> 3][q & 7], row[3][q >> 3][q & 7] };
            *(u16x4*)&KPt[rs + q][l4] = pk;
        }
    }
    {   // stage V^T (bf16 pass-through)
        const int d4 = (t & 15) * 4, ls = (t >> 4) * 4;
        u16x4 x[4];
#pragma unroll
        for (int i = 0; i < 4; ++i)
            x[i] = *(const u16x4*)&vb[(size_t)(bz * L_ + l0 + ls + i) * DM_ + h * 64 + d4];
#pragma unroll
        for (int q = 0; q < 4; ++q) {
            u16x4 pk = { x[0][q], x[1][q], x[2][q], x[3][q] };
            *(u16x4*)&Vt[d4 + q][ls] = pk;
        }
    }
    __syncthreads();

    f32x4 acc[4][4] = {};
#pragma unroll
    for (int ks = 0; ks < 2; ++ks) {
        bf16x8 af[4], bfr[4];
#pragma unroll
        for (int m = 0; m < 4; ++m)
            af[m] = *(const bf16x8*)&KPt[64 * w + 16 * m + lr][ks * 32 + lg * 8];
#pragma unroll
        for (int n = 0; n < 4; ++n)
            bfr[n] = *(const bf16x8*)&Vt[16 * n + lr][ks * 32 + lg * 8];
#pragma unroll
        for (int m = 0; m < 4; ++m)
#pragma unroll
            for (int n = 0; n < 4; ++n)
                acc[m][n] = __builtin_amdgcn_mfma_f32_16x16x32_bf16(af[m], bfr[n], acc[m][n], 0, 0, 0);
    }
    size_t sbase = ((size_t)(bh * NC_ + c)) * 64 * R_;
#pragma unroll
    for (int n = 0; n < 4; ++n)
#pragma unroll
        for (int m = 0; m < 4; ++m) {
            int d = 16 * n + lr;
            int r = 64 * w + 16 * m + lg * 4;
            u16x4 pk = { f2bu(acc[m][n][0]), f2bu(acc[m][n][1]),
                         f2bu(acc[m][n][2]), f2bu(acc[m][n][3]) };
            *(u16x4*)&kvT[sbase + (size_t)d * R_ + r] = pk;
        }
    {
        float s = 0.f;
#pragma unroll
        for (int j = 0; j < 8; ++j) {
            u16x8 vv = *(const u16x8*)&KPt[t][j * 8];
#pragma unroll
            for (int q = 0; q < 8; ++q) s += bu2f(vv[q]);
        }
        ksum[((size_t)(bh * NC_ + c)) * R_ + t] = s;
    }
}

// ---------------------------------------------------------------------------
// passB: exclusive prefix over chunks of kvT ([bh][c][d][r]) and ksum.
// Vectorized: one u16x4 chain per thread. grid (16, H, B).
// ---------------------------------------------------------------------------
__launch_bounds__(256)
__global__ void passB_chain(unsigned short* __restrict__ kvT, float* __restrict__ ksum) {
    const int bx = blockIdx.x, h = blockIdx.y, bz = blockIdx.z;
    const int t = threadIdx.x;
    const int bh = bz * H_ + h;
    const int idx = bx * 256 + t;        // [0, 4096)
    const int d = idx >> 6;
    const int rg = (idx & 63) * 4;
    size_t base = ((size_t)bh * NC_ * 64 + d) * R_ + rg;
    const size_t cstride = (size_t)64 * R_;
    float run0 = 0.f, run1 = 0.f, run2 = 0.f, run3 = 0.f;
    for (int c = 0; c < NC_; ++c) {
        size_t ix = base + (size_t)c * cstride;
        u16x4 v = *(const u16x4*)&kvT[ix];
        u16x4 o = { f2bu(run0), f2bu(run1), f2bu(run2), f2bu(run3) };
        *(u16x4*)&kvT[ix] = o;
        run0 += bu2f(v[0]); run1 += bu2f(v[1]);
        run2 += bu2f(v[2]); run3 += bu2f(v[3]);
    }
    if (bx == 0) {
        float rz = 0.f;
        for (int c = 0; c < NC_; ++c) {
            size_t ix = ((size_t)bh * NC_ + c) * R_ + t;
            float tmp = ksum[ix];
            ksum[ix] = rz;
            rz += tmp;
        }
    }
}

// ---------------------------------------------------------------------------
// passC (MFMA): prologue async Sl prefetch (pre-swizzled source); scores with
// register-hoisted bk; Spref from LDS + zu fragments; AV+den; bf16 out.
// ---------------------------------------------------------------------------
__launch_bounds__(256)
__global__ void passC_mfma(const unsigned short* __restrict__ qp, const unsigned short* __restrict__ kp,
                           const unsigned short* __restrict__ vb, const unsigned short* __restrict__ kvT,
                           const float* __restrict__ zpref, unsigned short* __restrict__ attnb) {
    __shared__ __align__(16) unsigned short Sl[64 * 256];  // 32 KB, swizzled kvT tile
    __shared__ __align__(16) unsigned short Vt[80][72];    // [d][l], row64=ones
    __shared__ __align__(16) unsigned short As[64][72];    // masked scores

    const int c = blockIdx.x, h = blockIdx.y, bz = blockIdx.z;
    const int t = threadIdx.x;
    const int lane = t & 63, w = t >> 6;
    const int lg = lane >> 4, lr = lane & 15;
    const int l0 = c * C_;
    const int bh = bz * H_ + h;
    const size_t sbase = ((size_t)(bh * NC_ + c)) * 64 * R_;
    const size_t zbase = ((size_t)(bh * NC_ + c)) * R_;

#pragma unroll
    for (int i = 0; i < 8; ++i) {
        int idx = i * 256 + t;
        int row = idx >> 5, s = idx & 31;
        gload16(&kvT[sbase + (size_t)row * R_ + ((s ^ (row & 7)) << 3)], &Sl[idx * 8]);
    }

    {   // stage V^T (bf16 pass-through)
        const int d4 = (t & 15) * 4, ls = (t >> 4) * 4;
        u16x4 x[4];
#pragma unroll
        for (int i = 0; i < 4; ++i)
            x[i] = *(const u16x4*)&vb[(size_t)(bz * L_ + l0 + ls + i) * DM_ + h * 64 + d4];
#pragma unroll
        for (int q = 0; q < 4; ++q) {
            u16x4 pk = { x[0][q], x[1][q], x[2][q], x[3][q] };
            *(u16x4*)&Vt[d4 + q][ls] = pk;
        }
    }
    if (t < 16) {
        u16x4 ones = { 0x3F80, 0x3F80, 0x3F80, 0x3F80 };
        *(u16x4*)&Vt[64][t * 4] = ones;
    }

    const size_t qrow = ((size_t)(bz * L_ + l0 + 16 * w + lr) * H_ + h) * R_;
    bf16x8 aq[8];
#pragma unroll
    for (int ks = 0; ks < 8; ++ks) aq[ks] = *(const bf16x8*)&qp[qrow + ks * 32 + lg * 8];

    // ---- scores: two half-hoists of 16 bk fragments each ----
    f32x4 sacc[4] = {};
#pragma unroll
    for (int half = 0; half < 2; ++half) {
        bf16x8 bk[4][4];
#pragma unroll
        for (int k2 = 0; k2 < 4; ++k2)
#pragma unroll
            for (int n = 0; n < 4; ++n)
                bk[k2][n] = *(const bf16x8*)&kp[((size_t)(bz * L_ + l0 + 16 * n + lr) * H_ + h) * R_
                                                + (half * 4 + k2) * 32 + lg * 8];
        __builtin_amdgcn_s_setprio(1);
#pragma unroll
        for (int k2 = 0; k2 < 4; ++k2)
#pragma unroll
            for (int n = 0; n < 4; ++n)
                sacc[n] = __builtin_amdgcn_mfma_f32_16x16x32_bf16(aq[half * 4 + k2], bk[k2][n], sacc[n], 0, 0, 0);
        __builtin_amdgcn_s_setprio(0);
    }
#pragma unroll
    for (int n = 0; n < 4; ++n)
#pragma unroll
        for (int ii = 0; ii < 4; ++ii) {
            int i_loc = 16 * w + lg * 4 + ii;
            int j_loc = 16 * n + lr;
            As[i_loc][j_loc] = (j_loc <= i_loc) ? f2bu(sacc[n][ii]) : (unsigned short)0;
        }

    u16x8 zu[8];
#pragma unroll
    for (int ks = 0; ks < 8; ++ks) {
        f4 z0 = *(const f4*)&zpref[zbase + ks * 32 + lg * 8];
        f4 z1 = *(const f4*)&zpref[zbase + ks * 32 + lg * 8 + 4];
        zu[ks] = u16x8{ f2bu(z0[0]), f2bu(z0[1]), f2bu(z0[2]), f2bu(z0[3]),
                        f2bu(z1[0]), f2bu(z1[1]), f2bu(z1[2]), f2bu(z1[3]) };
    }
    __syncthreads();

    f32x4 oacc[4] = {};
    f32x4 dacc = {};
    __builtin_amdgcn_s_setprio(1);
#pragma unroll
    for (int ks = 0; ks < 8; ++ks) {
#pragma unroll
        for (int n = 0; n < 4; ++n) {
            int row = 16 * n + lr;
            int slot = (ks * 4 + lg) ^ (lr & 7);
            bf16x8 bs = *(const bf16x8*)&Sl[row * 256 + slot * 8];
            oacc[n] = __builtin_amdgcn_mfma_f32_16x16x32_bf16(aq[ks], bs, oacc[n], 0, 0, 0);
        }
        dacc = __builtin_amdgcn_mfma_f32_16x16x32_bf16(aq[ks], *(bf16x8*)&zu[ks], dacc, 0, 0, 0);
    }

    f32x4 racc = {};
#pragma unroll
    for (int ks = 0; ks < 2; ++ks) {
        bf16x8 aa = *(const bf16x8*)&As[16 * w + lr][ks * 32 + lg * 8];
#pragma unroll
        for (int n = 0; n < 4; ++n) {
            bf16x8 bv = *(const bf16x8*)&Vt[16 * n + lr][ks * 32 + lg * 8];
            oacc[n] = __builtin_amdgcn_mfma_f32_16x16x32_bf16(aa, bv, oacc[n], 0, 0, 0);
        }
        bf16x8 b4 = *(const bf16x8*)&Vt[64 + lr][ks * 32 + lg * 8];
        racc = __builtin_amdgcn_mfma_f32_16x16x32_bf16(aa, b4, racc, 0, 0, 0);
    }
    __builtin_amdgcn_s_setprio(0);

#pragma unroll
    for (int ii = 0; ii < 4; ++ii) {
        float rs_ = __shfl(racc[ii], lane & 48, 64);
        float den = rs_ + dacc[ii];
        float inv = 1.f / (fmaxf(den, 1e-6f) + 1e-6f);
#pragma unroll
        for (int n = 0; n < 4; ++n)
            attnb[(size_t)(bz * L_ + l0 + 16 * w + lg * 4 + ii) * DM_ + h * 64 + 16 * n + lr] =
                f2bu(oacc[n][ii] * inv);
    }
}

// ---------------------------------------------------------------------------
// In-place row LayerNorm over last dim (1024), eps=1e-5.
// ---------------------------------------------------------------------------
__launch_bounds__(256)
__global__ void ln_kernel(float* __restrict__ io, const float* __restrict__ gamma,
                          const float* __restrict__ beta) {
    __shared__ float wsum[4], wsum2[4];
    const int row = blockIdx.x;
    const int t = threadIdx.x;
    f4 x = *(const f4*)&io[(size_t)row * DM_ + t * 4];
    float s  = x[0] + x[1] + x[2] + x[3];
    float s2 = x[0]*x[0] + x[1]*x[1] + x[2]*x[2] + x[3]*x[3];
#pragma unroll
    for (int o = 32; o > 0; o >>= 1) {
        s  += __shfl_down(s, o);
        s2 += __shfl_down(s2, o);
    }
    if ((t & 63) == 0) { wsum[t >> 6] = s; wsum2[t >> 6] = s2; }
    __syncthreads();
    s  = wsum[0]  + wsum[1]  + wsum[2]  + wsum[3];
    s2 = wsum2[0] + wsum2[1] + wsum2[2] + wsum2[3];
    const float m = s * (1.f / DM_);
    const float var = s2 * (1.f / DM_) - m * m;
    const float rstd = rsqrtf(var + 1e-5f);
    f4 g  = *(const f4*)&gamma[t * 4];
    f4 bb = *(const f4*)&beta[t * 4];
    f4 o = (x - m) * rstd * g + bb;
    *(f4*)&io[(size_t)row * DM_ + t * 4] = o;
}

// ---------------------------------------------------------------------------
// Workspace (226 MB), staged aliasing (audited, same as round 11/14/17):
//  persistent: qp[0,64) kp[64,128) kvT[128,192) vb[192,208) attnb[208,224) ksum[224,226)
//  QKV phase:  aq[0,16) ak[16,32) av[32,48) wq[48,50) wk[50,52) wv[52,54)
//              outputs qx[128,144) kx[144,160) vb[192,208)
//  om_bf at [208,208.07) (attnb slot; dead before passC writes attnb)
//  feat: reads qx/kx+om, writes qp[0,64) + kp[64,128)
//  passA: writes kvT[128,192) ; wo_bf[64,66) after passC (kp dead)
// ---------------------------------------------------------------------------
extern "C" void kernel_launch(void* const* d_in, const int* in_sizes, int n_in,
                              void* d_out, int out_size, void* d_ws, size_t ws_size,
                              hipStream_t stream) {
    const float* pre_q = (const float*)d_in[0];
    const float* pre_k = (const float*)d_in[1];
    const float* pre_v = (const float*)d_in[2];
    const float* wq    = (const float*)d_in[3];
    const float* wk    = (const float*)d_in[4];
    const float* wv    = (const float*)d_in[5];
    const float* wo    = (const float*)d_in[6];
    const float* gamma = (const float*)d_in[7];
    const float* beta  = (const float*)d_in[8];
    const float* omega = (const float*)d_in[9];
    const float* bvec  = (const float*)d_in[10];

    const size_t NEED = 226ull << 20;
    if (ws_size < NEED) return;

    char* w = (char*)d_ws;
    unsigned short* qp    = (unsigned short*)(w);
    unsigned short* kp    = (unsigned short*)(w + (64ull << 20));
    unsigned short* kvT   = (unsigned short*)(w + (128ull << 20));
    unsigned short* vb    = (unsigned short*)(w + (192ull << 20));
    unsigned short* attnb = (unsigned short*)(w + (208ull << 20));
    float*          ksum  = (float*)(w + (224ull << 20));
    // transients
    unsigned short* aq    = (unsigned short*)(w);
    unsigned short* ak    = (unsigned short*)(w + (16ull << 20));
    unsigned short* av    = (unsigned short*)(w + (32ull << 20));
    unsigned short* wq_bf = (unsigned short*)(w + (48ull << 20));
    unsigned short* wk_bf = (unsigned short*)(w + (50ull << 20));
    unsigned short* wv_bf = (unsigned short*)(w + (52ull << 20));
    unsigned short* qx    = (unsigned short*)(w + (128ull << 20));
    unsigned short* kx    = (unsigned short*)(w + (144ull << 20));
    unsigned short* om_bf = (unsigned short*)(w + (208ull << 20));
    unsigned short* wo_bf = (unsigned short*)(w + (64ull << 20));
    float*          outb  = (float*)d_out;

    const int n4_big = M_ * DM_ / 4;
    const int n4_w   = DM_ * DM_ / 4;
    const int n4_om  = R_ * D_ / 4;
    dim3 gg3(DM_ / 128, M_ / 128, 3);   // 1536 blocks
    dim3 ggo(DM_ / 128, M_ / 64);       // out-proj: 1024 blocks

    cvt_bf16_x3<<<dim3((n4_big + 255) / 256, 1, 3), 256, 0, stream>>>(
        pre_q, pre_k, pre_v, aq, ak, av, n4_big);
    cvt_bf16_x4<<<dim3((n4_w + 255) / 256, 1, 4), 256, 0, stream>>>(
        wq, wk, wv, omega, wq_bf, wk_bf, wv_bf, om_bf, n4_w, n4_om);

    gemm_mfma_b3<<<gg3, 256, 0, stream>>>(aq, ak, av, wq_bf, wk_bf, wv_bf,
                                          qx, kx, vb, M_, DM_, DM_);
    feat_mfma_b2<<<dim3(M2_ / 64, 1, 2), 256, 0, stream>>>(qx, kx, om_bf, bvec, qp, kp);

    passA_mfma<<<dim3(NC_, H_, B_), 256, 0, stream>>>(kp, vb, kvT, ksum);
    passB_chain<<<dim3(16, H_, B_), 256, 0, stream>>>(kvT, ksum);
    passC_mfma<<<dim3(NC_, H_, B_), 256, 0, stream>>>(qp, kp, vb, kvT, ksum, attnb);

    cvt_bf16<<<(n4_w + 255) / 256, 256, 0, stream>>>(wo, wo_bf, n4_w);
    gemm_out<<<ggo, 256, 0, stream>>>(attnb, wo_bf, pre_q, outb, M_, DM_, DM_);
    ln_kernel<<<M_, 256, 0, stream>>>(outb, gamma, beta);
}

// Round 20
// 286.889 us; speedup vs baseline: 1.1400x; 1.0138x over previous
//
#include <hip/hip_runtime.h>
#include <hip/hip_bf16.h>

// Performer (ORF linear attention) + out-proj + residual + LayerNorm.
// Round 20: out-proj GEMM restored to the validated 128x128 3-ring
// counted-vmcnt structure (same as gemm_mfma_b3) with fp32+resid epilogue.
// Everything else identical to round 17/19 (best measured).

typedef float f4 __attribute__((ext_vector_type(4)));
typedef __attribute__((ext_vector_type(8))) short bf16x8;
typedef __attribute__((ext_vector_type(4))) float f32x4;
typedef unsigned short u16x4 __attribute__((ext_vector_type(4)));
typedef unsigned short u16x8 __attribute__((ext_vector_type(8)));

#define B_  4
#define L_  2048
#define H_  16
#define D_  64
#define DM_ 1024
#define R_  256
#define C_  64
#define NC_ (L_ / C_)
#define M_  (B_ * L_)
#define M2_ (M_ * H_)

static __device__ __forceinline__ unsigned short f2bu(float x) {
    __hip_bfloat16 h = __float2bfloat16(x);
    return *(unsigned short*)&h;
}
static __device__ __forceinline__ float bu2f(unsigned short u) {
    union { unsigned int i; float f; } c; c.i = ((unsigned int)u) << 16; return c.f;
}

typedef __attribute__((address_space(3))) void lds_void_t;
typedef __attribute__((address_space(1))) const void gvoid_t;
static __device__ __forceinline__ void gload16(const void* g, void* l) {
    __builtin_amdgcn_global_load_lds((gvoid_t*)g, (lds_void_t*)l, 16, 0, 0);
}

// ---------------------------------------------------------------------------
// fp32 -> bf16 casts: single, 3-way and 4-way batched variants
// ---------------------------------------------------------------------------
__launch_bounds__(256)
__global__ void cvt_bf16(const float* __restrict__ in, unsigned short* __restrict__ out, int n4) {
    int i = blockIdx.x * 256 + threadIdx.x;
    if (i < n4) {
        f4 v = *(const f4*)&in[(size_t)i * 4];
        ushort4 o;
        o.x = f2bu(v[0]); o.y = f2bu(v[1]); o.z = f2bu(v[2]); o.w = f2bu(v[3]);
        *(ushort4*)&out[(size_t)i * 4] = o;
    }
}

__launch_bounds__(256)
__global__ void cvt_bf16_x3(const float* __restrict__ i0, const float* __restrict__ i1,
                            const float* __restrict__ i2,
                            unsigned short* __restrict__ o0, unsigned short* __restrict__ o1,
                            unsigned short* __restrict__ o2, int n4) {
    const int z = blockIdx.z;
    const float* in = (z == 0) ? i0 : (z == 1) ? i1 : i2;
    unsigned short* out = (z == 0) ? o0 : (z == 1) ? o1 : o2;
    int i = blockIdx.x * 256 + threadIdx.x;
    if (i < n4) {
        f4 v = *(const f4*)&in[(size_t)i * 4];
        ushort4 o;
        o.x = f2bu(v[0]); o.y = f2bu(v[1]); o.z = f2bu(v[2]); o.w = f2bu(v[3]);
        *(ushort4*)&out[(size_t)i * 4] = o;
    }
}

__launch_bounds__(256)
__global__ void cvt_bf16_x4(const float* __restrict__ i0, const float* __restrict__ i1,
                            const float* __restrict__ i2, const float* __restrict__ i3,
                            unsigned short* __restrict__ o0, unsigned short* __restrict__ o1,
                            unsigned short* __restrict__ o2, unsigned short* __restrict__ o3,
                            int n4_abc, int n4_d) {
    const int z = blockIdx.z;
    const float* in = (z == 0) ? i0 : (z == 1) ? i1 : (z == 2) ? i2 : i3;
    unsigned short* out = (z == 0) ? o0 : (z == 1) ? o1 : (z == 2) ? o2 : o3;
    const int n4 = (z == 3) ? n4_d : n4_abc;
    int i = blockIdx.x * 256 + threadIdx.x;
    if (i < n4) {
        f4 v = *(const f4*)&in[(size_t)i * 4];
        ushort4 o;
        o.x = f2bu(v[0]); o.y = f2bu(v[1]); o.z = f2bu(v[2]); o.w = f2bu(v[3]);
        *(ushort4*)&out[(size_t)i * 4] = o;
    }
}

// ---------------------------------------------------------------------------
// Batched (z=0..2) C_z = A_z @ B_z^T, bf16 out, 128x128 tile, BK=32.
// 3-deep LDS ring, counted vmcnt (loads span barriers), XOR-swizzled tiles.
// ---------------------------------------------------------------------------
__launch_bounds__(256)
__global__ void gemm_mfma_b3(const unsigned short* __restrict__ A0, const unsigned short* __restrict__ A1,
                             const unsigned short* __restrict__ A2,
                             const unsigned short* __restrict__ B0, const unsigned short* __restrict__ B1,
                             const unsigned short* __restrict__ B2,
                             unsigned short* __restrict__ C0, unsigned short* __restrict__ C1,
                             unsigned short* __restrict__ C2,
                             int M, int N, int K) {
    __shared__ unsigned short Asl[3][128 * 32];   // 3 x 8 KB
    __shared__ unsigned short Bsl[3][128 * 32];   // 3 x 8 KB
    const int z = blockIdx.z;
    const unsigned short* A  = (z == 0) ? A0 : (z == 1) ? A1 : A2;
    const unsigned short* Bw = (z == 0) ? B0 : (z == 1) ? B1 : B2;
    unsigned short*       Cb = (z == 0) ? C0 : (z == 1) ? C1 : C2;
    const int t = threadIdx.x;
    const int lane = t & 63, w = t >> 6;
    const int wr = w >> 1, wc = w & 1;
    const int nwg = gridDim.x * gridDim.y;
    const int bid = blockIdx.y * gridDim.x + blockIdx.x;
    const int cpx = nwg >> 3;
    const int swz = (bid & 7) * cpx + (bid >> 3);
    const int row0 = (swz / gridDim.x) * 128, col0 = (swz % gridDim.x) * 128;
    const int sr0 = t >> 2;
    const int ssw = (((t & 3) ^ ((t >> 3) & 3)) * 8);   // pre-swizzled source chunk
    const int lg = lane >> 4, lr = lane & 15;
    const int aslot = (lg ^ ((lr >> 1) & 3)) * 8;       // swizzled read slot

#define STAGE_B3(buf, kkk) do { \
        gload16(&A [(size_t)(row0 + sr0)      * K + (kkk) + ssw], &Asl[buf][t * 8]); \
        gload16(&A [(size_t)(row0 + sr0 + 64) * K + (kkk) + ssw], &Asl[buf][(t + 256) * 8]); \
        gload16(&Bw[(size_t)(col0 + sr0)      * K + (kkk) + ssw], &Bsl[buf][t * 8]); \
        gload16(&Bw[(size_t)(col0 + sr0 + 64) * K + (kkk) + ssw], &Bsl[buf][(t + 256) * 8]); \
    } while (0)
#define COMPUTE_B3(buf) do { \
        bf16x8 af[4], bfr[4]; \
        _Pragma("unroll") \
        for (int m = 0; m < 4; ++m) \
            af[m] = *(const bf16x8*)&Asl[buf][(wr * 64 + m * 16 + lr) * 32 + aslot]; \
        _Pragma("unroll") \
        for (int n = 0; n < 4; ++n) \
            bfr[n] = *(const bf16x8*)&Bsl[buf][(wc * 64 + n * 16 + lr) * 32 + aslot]; \
        _Pragma("unroll") \
        for (int m = 0; m < 4; ++m) \
            _Pragma("unroll") \
            for (int n = 0; n < 4; ++n) \
                acc[m][n] = __builtin_amdgcn_mfma_f32_16x16x32_bf16(af[m], bfr[n], acc[m][n], 0, 0, 0); \
    } while (0)

    f32x4 acc[4][4] = {};
    STAGE_B3(0, 0);
    STAGE_B3(1, 32);
    int cur = 0;
    for (int kk = 0; kk + 64 < K; kk += 32) {
        int nx = cur + 2; if (nx >= 3) nx -= 3;
        STAGE_B3(nx, kk + 64);
        asm volatile("s_waitcnt vmcnt(8)" ::: "memory");
        __builtin_amdgcn_sched_barrier(0);
        __builtin_amdgcn_s_barrier();
        COMPUTE_B3(cur);
        __builtin_amdgcn_s_barrier();
        cur = (cur == 2) ? 0 : cur + 1;
    }
    asm volatile("s_waitcnt vmcnt(4)" ::: "memory");
    __builtin_amdgcn_sched_barrier(0);
    __builtin_amdgcn_s_barrier();
    COMPUTE_B3(cur);
    __builtin_amdgcn_s_barrier();
    cur = (cur == 2) ? 0 : cur + 1;
    asm volatile("s_waitcnt vmcnt(0)" ::: "memory");
    __builtin_amdgcn_sched_barrier(0);
    __builtin_amdgcn_s_barrier();
    COMPUTE_B3(cur);
#undef STAGE_B3
#undef COMPUTE_B3
#pragma unroll
    for (int m = 0; m < 4; ++m)
#pragma unroll
        for (int n = 0; n < 4; ++n)
#pragma unroll
            for (int i = 0; i < 4; ++i) {
                int r  = row0 + wr * 64 + m * 16 + lg * 4 + i;
                int cc = col0 + wc * 64 + n * 16 + lr;
                Cb[(size_t)r * N + cc] = f2bu(acc[m][n][i]);
            }
}

// ---------------------------------------------------------------------------
// Out-proj GEMM: C = A @ B^T + fp32 resid, fp32 out. 128x128 tile, BK=32,
// 3-deep ring, counted vmcnt (same validated structure as gemm_mfma_b3).
// 512 blocks (2/CU, fully co-resident).
// ---------------------------------------------------------------------------
__launch_bounds__(256)
__global__ void gemm_out(const unsigned short* __restrict__ A,
                         const unsigned short* __restrict__ Bw,
                         const float* __restrict__ resid,
                         float* __restrict__ Cf,
                         int M, int N, int K) {
    __shared__ unsigned short Asl[3][128 * 32];   // 3 x 8 KB
    __shared__ unsigned short Bsl[3][128 * 32];   // 3 x 8 KB
    const int t = threadIdx.x;
    const int lane = t & 63, w = t >> 6;
    const int wr = w >> 1, wc = w & 1;
    const int nwg = gridDim.x * gridDim.y;        // 512, divisible by 8
    const int bid = blockIdx.y * gridDim.x + blockIdx.x;
    const int cpx = nwg >> 3;
    const int swz = (bid & 7) * cpx + (bid >> 3);
    const int row0 = (swz / gridDim.x) * 128, col0 = (swz % gridDim.x) * 128;
    const int sr0 = t >> 2;
    const int ssw = (((t & 3) ^ ((t >> 3) & 3)) * 8);
    const int lg = lane >> 4, lr = lane & 15;
    const int aslot = (lg ^ ((lr >> 1) & 3)) * 8;

#define STAGE_O(buf, kkk) do { \
        gload16(&A [(size_t)(row0 + sr0)      * K + (kkk) + ssw], &Asl[buf][t * 8]); \
        gload16(&A [(size_t)(row0 + sr0 + 64) * K + (kkk) + ssw], &Asl[buf][(t + 256) * 8]); \
        gload16(&Bw[(size_t)(col0 + sr0)      * K + (kkk) + ssw], &Bsl[buf][t * 8]); \
        gload16(&Bw[(size_t)(col0 + sr0 + 64) * K + (kkk) + ssw], &Bsl[buf][(t + 256) * 8]); \
    } while (0)
#define COMPUTE_O(buf) do { \
        bf16x8 af[4], bfr[4]; \
        _Pragma("unroll") \
        for (int m = 0; m < 4; ++m) \
            af[m] = *(const bf16x8*)&Asl[buf][(wr * 64 + m * 16 + lr) * 32 + aslot]; \
        _Pragma("unroll") \
        for (int n = 0; n < 4; ++n) \
            bfr[n] = *(const bf16x8*)&Bsl[buf][(wc * 64 + n * 16 + lr) * 32 + aslot]; \
        _Pragma("unroll") \
        for (int m = 0; m < 4; ++m) \
            _Pragma("unroll") \
            for (int n = 0; n < 4; ++n) \
                acc[m][n] = __builtin_amdgcn_mfma_f32_16x16x32_bf16(af[m], bfr[n], acc[m][n], 0, 0, 0); \
    } while (0)

    f32x4 acc[4][4] = {};
    STAGE_O(0, 0);
    STAGE_O(1, 32);
    int cur = 0;
    for (int kk = 0; kk + 64 < K; kk += 32) {
        int nx = cur + 2; if (nx >= 3) nx -= 3;
        STAGE_O(nx, kk + 64);
        asm volatile("s_waitcnt vmcnt(8)" ::: "memory");
        __builtin_amdgcn_sched_barrier(0);
        __builtin_amdgcn_s_barrier();
        COMPUTE_O(cur);
        __builtin_amdgcn_s_barrier();
        cur = (cur == 2) ? 0 : cur + 1;
    }
    asm volatile("s_waitcnt vmcnt(4)" ::: "memory");
    __builtin_amdgcn_sched_barrier(0);
    __builtin_amdgcn_s_barrier();
    COMPUTE_O(cur);
    __builtin_amdgcn_s_barrier();
    cur = (cur == 2) ? 0 : cur + 1;
    asm volatile("s_waitcnt vmcnt(0)" ::: "memory");
    __builtin_amdgcn_sched_barrier(0);
    __builtin_amdgcn_s_barrier();
    COMPUTE_O(cur);
#undef STAGE_O
#undef COMPUTE_O
#pragma unroll
    for (int m = 0; m < 4; ++m)
#pragma unroll
        for (int n = 0; n < 4; ++n)
#pragma unroll
            for (int i = 0; i < 4; ++i) {
                int r  = row0 + wr * 64 + m * 16 + lg * 4 + i;
                int cc = col0 + wc * 64 + n * 16 + lr;
                size_t off = (size_t)r * N + cc;
                Cf[off] = acc[m][n][i] + resid[off];
            }
}

// ---------------------------------------------------------------------------
// Batched (z=0..1) feat: out[m,r] = bf16(sqrt(2/R)*cos(dot(X[m],om[r]) + b[r]))
// Xs and Pool(omega) XOR-swizzled; Pool reused as repack buffer.
// ---------------------------------------------------------------------------
#define RS_STRIDE 272
__launch_bounds__(256)
__global__ void feat_mfma_b2(const unsigned short* __restrict__ X0, const unsigned short* __restrict__ X1,
                             const unsigned short* __restrict__ om,
                             const float* __restrict__ bvec,
                             unsigned short* __restrict__ O0, unsigned short* __restrict__ O1) {
    __shared__ unsigned short Xs[2 * 64 * 32];        // 8 KB
    __shared__ unsigned short Pool[64 * RS_STRIDE];   // 34 KB: Os then Rs
    const int z = blockIdx.z;
    const unsigned short* X = z ? X1 : X0;
    unsigned short* out = z ? O1 : O0;
    const int t = threadIdx.x;
    const int lane = t & 63, w = t >> 6;
    const int lg = lane >> 4, lr = lane & 15;
    const int m0 = blockIdx.x * 64;
    const int aslot = (lg ^ ((lr >> 1) & 3)) * 8;

#pragma unroll
    for (int i = 0; i < 2; ++i) {
        int cch = i * 256 + t;
        int ks = cch >> 8, row = (cch >> 2) & 63;
        int sub = ((cch & 3) ^ ((cch >> 3) & 3)) * 8;   // pre-swizzled source
        gload16(&X[(size_t)(m0 + row) * 64 + ks * 32 + sub], &Xs[cch * 8]);
    }
#pragma unroll
    for (int i = 0; i < 8; ++i) {
        int cch = i * 256 + t;
        int ks = cch >> 10, r = (cch >> 2) & 255;
        int sub = ((cch & 3) ^ ((cch >> 3) & 3)) * 8;
        gload16(&om[(size_t)r * 64 + ks * 32 + sub], &Pool[cch * 8]);
    }
    __syncthreads();

    f32x4 acc[4][4] = {};
#pragma unroll
    for (int ks = 0; ks < 2; ++ks) {
        bf16x8 af[4], bfr[4];
#pragma unroll
        for (int m = 0; m < 4; ++m)
            af[m] = *(const bf16x8*)&Xs[ks * 2048 + (m * 16 + lr) * 32 + aslot];
#pragma unroll
        for (int n = 0; n < 4; ++n)
            bfr[n] = *(const bf16x8*)&Pool[ks * 8192 + (w * 64 + n * 16 + lr) * 32 + aslot];
#pragma unroll
        for (int m = 0; m < 4; ++m)
#pragma unroll
            for (int n = 0; n < 4; ++n)
                acc[m][n] = __builtin_amdgcn_mfma_f32_16x16x32_bf16(af[m], bfr[n], acc[m][n], 0, 0, 0);
    }
    __syncthreads();   // omega reads done; Pool becomes repack buffer

    const float scale = 0.08838834764831845f;  // sqrt(2/256)
#pragma unroll
    for (int n = 0; n < 4; ++n) {
        const int col = w * 64 + n * 16 + lr;
        const float bb = bvec[col];
#pragma unroll
        for (int m = 0; m < 4; ++m)
#pragma unroll
            for (int ii = 0; ii < 4; ++ii)
                Pool[(m * 16 + lg * 4 + ii) * RS_STRIDE + col] = f2bu(scale * __cosf(acc[m][n][ii] + bb));
    }
    __syncthreads();
#pragma unroll
    for (int i = 0; i < 8; ++i) {
        int cch = i * 256 + t;
        int row = cch >> 5, colc = (cch & 31) * 8;
        u16x8 vv = *(const u16x8*)&Pool[row * RS_STRIDE + colc];
        *(u16x8*)&out[(size_t)(m0 + row) * 256 + colc] = vv;
    }
}

// ---------------------------------------------------------------------------
// passA (MFMA): kvT[bh][c][d][r] = sum_l kp[l][r]*vb[l][d] (bf16), ksum[r].
// ---------------------------------------------------------------------------
__launch_bounds__(256)
__global__ void passA_mfma(const unsigned short* __restrict__ kp, const unsigned short* __restrict__ vb,
                           unsigned short* __restrict__ kvT, float* __restrict__ ksum) {
    __shared__ __align__(16) unsigned short KPt[256][72];  // [r][l]
    __shared__ __align__(16) unsigned short Vt[64][72];    // [d][l]
    const int c = blockIdx.x, h = blockIdx.y, bz = blockIdx.z;
    const int t = threadIdx.x;
    const int lane = t & 63, w = t >> 6;
    const int lg = lane >> 4, lr = lane & 15;
    const int l0 = c * C_;
    const int bh = bz * H_ + h;

    {   // stage KP^T
        const int l4 = (t & 15) * 4, rs = (t >> 4) * 16;
        u16x8 row[4][2];
#pragma unroll
        for (int i = 0; i < 4; ++i) {
            const unsigned short* src = &kp[((size_t)(bz * L_ + l0 + l4 + i) * H_ + h) * R_ + rs];
            row[i][0] = *(const u16x8*)src;
            row[i][1] = *(const u16x8*)(src + 8);
        }
#pragma unroll
        for (int q = 0; q < 16; ++q) {
            u16x4 pk = { row[0][q >> 3][q & 7], row[1][q >> 3][q & 7],
                         row[2][q >> 3][q & 7], row[3][q >> 3][q & 7] };
            *(u16x4*)&KPt[rs + q][l4] = pk;
        }
    }
    {   // stage V^T (bf16 pass-through)
        const int d4 = (t & 15) * 4, ls = (t >> 4) * 4;
        u16x4 x[4];
#pragma unroll
        for (int i = 0; i < 4; ++i)
            x[i] = *(const u16x4*)&vb[(size_t)(bz * L_ + l0 + ls + i) * DM_ + h * 64 + d4];
#pragma unroll
        for (int q = 0; q < 4; ++q) {
            u16x4 pk = { x[0][q], x[1][q], x[2][q], x[3][q] };
            *(u16x4*)&Vt[d4 + q][ls] = pk;
        }
    }
    __syncthreads();

    f32x4 acc[4][4] = {};
#pragma unroll
    for (int ks = 0; ks < 2; ++ks) {
        bf16x8 af[4], bfr[4];
#pragma unroll
        for (int m = 0; m < 4; ++m)
            af[m] = *(const bf16x8*)&KPt[64 * w + 16 * m + lr][ks * 32 + lg * 8];
#pragma unroll
        for (int n = 0; n < 4; ++n)
            bfr[n] = *(const bf16x8*)&Vt[16 * n + lr][ks * 32 + lg * 8];
#pragma unroll
        for (int m = 0; m < 4; ++m)
#pragma unroll
            for (int n = 0; n < 4; ++n)
                acc[m][n] = __builtin_amdgcn_mfma_f32_16x16x32_bf16(af[m], bfr[n], acc[m][n], 0, 0, 0);
    }
    size_t sbase = ((size_t)(bh * NC_ + c)) * 64 * R_;
#pragma unroll
    for (int n = 0; n < 4; ++n)
#pragma unroll
        for (int m = 0; m < 4; ++m) {
            int d = 16 * n + lr;
            int r = 64 * w + 16 * m + lg * 4;
            u16x4 pk = { f2bu(acc[m][n][0]), f2bu(acc[m][n][1]),
                         f2bu(acc[m][n][2]), f2bu(acc[m][n][3]) };
            *(u16x4*)&kvT[sbase + (size_t)d * R_ + r] = pk;
        }
    {
        float s = 0.f;
#pragma unroll
        for (int j = 0; j < 8; ++j) {
            u16x8 vv = *(const u16x8*)&KPt[t][j * 8];
#pragma unroll
            for (int q = 0; q < 8; ++q) s += bu2f(vv[q]);
        }
        ksum[((size_t)(bh * NC_ + c)) * R_ + t] = s;
    }
}

// ---------------------------------------------------------------------------
// passB: exclusive prefix over chunks of kvT ([bh][c][d][r]) and ksum.
// Vectorized: one u16x4 chain per thread. grid (16, H, B).
// ---------------------------------------------------------------------------
__launch_bounds__(256)
__global__ void passB_chain(unsigned short* __restrict__ kvT, float* __restrict__ ksum) {
    const int bx = blockIdx.x, h = blockIdx.y, bz = blockIdx.z;
    const int t = threadIdx.x;
    const int bh = bz * H_ + h;
    const int idx = bx * 256 + t;        // [0, 4096)
    const int d = idx >> 6;
    const int rg = (idx & 63) * 4;
    size_t base = ((size_t)bh * NC_ * 64 + d) * R_ + rg;
    const size_t cstride = (size_t)64 * R_;
    float run0 = 0.f, run1 = 0.f, run2 = 0.f, run3 = 0.f;
    for (int c = 0; c < NC_; ++c) {
        size_t ix = base + (size_t)c * cstride;
        u16x4 v = *(const u16x4*)&kvT[ix];
        u16x4 o = { f2bu(run0), f2bu(run1), f2bu(run2), f2bu(run3) };
        *(u16x4*)&kvT[ix] = o;
        run0 += bu2f(v[0]); run1 += bu2f(v[1]);
        run2 += bu2f(v[2]); run3 += bu2f(v[3]);
    }
    if (bx == 0) {
        float rz = 0.f;
        for (int c = 0; c < NC_; ++c) {
            size_t ix = ((size_t)bh * NC_ + c) * R_ + t;
            float tmp = ksum[ix];
            ksum[ix] = rz;
            rz += tmp;
        }
    }
}

// ---------------------------------------------------------------------------
// passC (MFMA): prologue async Sl prefetch (pre-swizzled source); scores with
// register-hoisted bk; Spref from LDS + zu fragments; AV+den; bf16 out.
// ---------------------------------------------------------------------------
__launch_bounds__(256)
__global__ void passC_mfma(const unsigned short* __restrict__ qp, const unsigned short* __restrict__ kp,
                           const unsigned short* __restrict__ vb, const unsigned short* __restrict__ kvT,
                           const float* __restrict__ zpref, unsigned short* __restrict__ attnb) {
    __shared__ __align__(16) unsigned short Sl[64 * 256];  // 32 KB, swizzled kvT tile
    __shared__ __align__(16) unsigned short Vt[80][72];    // [d][l], row64=ones
    __shared__ __align__(16) unsigned short As[64][72];    // masked scores

    const int c = blockIdx.x, h = blockIdx.y, bz = blockIdx.z;
    const int t = threadIdx.x;
    const int lane = t & 63, w = t >> 6;
    const int lg = lane >> 4, lr = lane & 15;
    const int l0 = c * C_;
    const int bh = bz * H_ + h;
    const size_t sbase = ((size_t)(bh * NC_ + c)) * 64 * R_;
    const size_t zbase = ((size_t)(bh * NC_ + c)) * R_;

#pragma unroll
    for (int i = 0; i < 8; ++i) {
        int idx = i * 256 + t;
        int row = idx >> 5, s = idx & 31;
        gload16(&kvT[sbase + (size_t)row * R_ + ((s ^ (row & 7)) << 3)], &Sl[idx * 8]);
    }

    {   // stage V^T (bf16 pass-through)
        const int d4 = (t & 15) * 4, ls = (t >> 4) * 4;
        u16x4 x[4];
#pragma unroll
        for (int i = 0; i < 4; ++i)
            x[i] = *(const u16x4*)&vb[(size_t)(bz * L_ + l0 + ls + i) * DM_ + h * 64 + d4];
#pragma unroll
        for (int q = 0; q < 4; ++q) {
            u16x4 pk = { x[0][q], x[1][q], x[2][q], x[3][q] };
            *(u16x4*)&Vt[d4 + q][ls] = pk;
        }
    }
    if (t < 16) {
        u16x4 ones = { 0x3F80, 0x3F80, 0x3F80, 0x3F80 };
        *(u16x4*)&Vt[64][t * 4] = ones;
    }

    const size_t qrow = ((size_t)(bz * L_ + l0 + 16 * w + lr) * H_ + h) * R_;
    bf16x8 aq[8];
#pragma unroll
    for (int ks = 0; ks < 8; ++ks) aq[ks] = *(const bf16x8*)&qp[qrow + ks * 32 + lg * 8];

    // ---- scores: two half-hoists of 16 bk fragments each ----
    f32x4 sacc[4] = {};
#pragma unroll
    for (int half = 0; half < 2; ++half) {
        bf16x8 bk[4][4];
#pragma unroll
        for (int k2 = 0; k2 < 4; ++k2)
#pragma unroll
            for (int n = 0; n < 4; ++n)
                bk[k2][n] = *(const bf16x8*)&kp[((size_t)(bz * L_ + l0 + 16 * n + lr) * H_ + h) * R_
                                                + (half * 4 + k2) * 32 + lg * 8];
        __builtin_amdgcn_s_setprio(1);
#pragma unroll
        for (int k2 = 0; k2 < 4; ++k2)
#pragma unroll
            for (int n = 0; n < 4; ++n)
                sacc[n] = __builtin_amdgcn_mfma_f32_16x16x32_bf16(aq[half * 4 + k2], bk[k2][n], sacc[n], 0, 0, 0);
        __builtin_amdgcn_s_setprio(0);
    }
#pragma unroll
    for (int n = 0; n < 4; ++n)
#pragma unroll
        for (int ii = 0; ii < 4; ++ii) {
            int i_loc = 16 * w + lg * 4 + ii;
            int j_loc = 16 * n + lr;
            As[i_loc][j_loc] = (j_loc <= i_loc) ? f2bu(sacc[n][ii]) : (unsigned short)0;
        }

    u16x8 zu[8];
#pragma unroll
    for (int ks = 0; ks < 8; ++ks) {
        f4 z0 = *(const f4*)&zpref[zbase + ks * 32 + lg * 8];
        f4 z1 = *(const f4*)&zpref[zbase + ks * 32 + lg * 8 + 4];
        zu[ks] = u16x8{ f2bu(z0[0]), f2bu(z0[1]), f2bu(z0[2]), f2bu(z0[3]),
                        f2bu(z1[0]), f2bu(z1[1]), f2bu(z1[2]), f2bu(z1[3]) };
    }
    __syncthreads();

    f32x4 oacc[4] = {};
    f32x4 dacc = {};
    __builtin_amdgcn_s_setprio(1);
#pragma unroll
    for (int ks = 0; ks < 8; ++ks) {
#pragma unroll
        for (int n = 0; n < 4; ++n) {
            int row = 16 * n + lr;
            int slot = (ks * 4 + lg) ^ (lr & 7);
            bf16x8 bs = *(const bf16x8*)&Sl[row * 256 + slot * 8];
            oacc[n] = __builtin_amdgcn_mfma_f32_16x16x32_bf16(aq[ks], bs, oacc[n], 0, 0, 0);
        }
        dacc = __builtin_amdgcn_mfma_f32_16x16x32_bf16(aq[ks], *(bf16x8*)&zu[ks], dacc, 0, 0, 0);
    }

    f32x4 racc = {};
#pragma unroll
    for (int ks = 0; ks < 2; ++ks) {
        bf16x8 aa = *(const bf16x8*)&As[16 * w + lr][ks * 32 + lg * 8];
#pragma unroll
        for (int n = 0; n < 4; ++n) {
            bf16x8 bv = *(const bf16x8*)&Vt[16 * n + lr][ks * 32 + lg * 8];
            oacc[n] = __builtin_amdgcn_mfma_f32_16x16x32_bf16(aa, bv, oacc[n], 0, 0, 0);
        }
        bf16x8 b4 = *(const bf16x8*)&Vt[64 + lr][ks * 32 + lg * 8];
        racc = __builtin_amdgcn_mfma_f32_16x16x32_bf16(aa, b4, racc, 0, 0, 0);
    }
    __builtin_amdgcn_s_setprio(0);

#pragma unroll
    for (int ii = 0; ii < 4; ++ii) {
        float rs_ = __shfl(racc[ii], lane & 48, 64);
        float den = rs_ + dacc[ii];
        float inv = 1.f / (fmaxf(den, 1e-6f) + 1e-6f);
#pragma unroll
        for (int n = 0; n < 4; ++n)
            attnb[(size_t)(bz * L_ + l0 + 16 * w + lg * 4 + ii) * DM_ + h * 64 + 16 * n + lr] =
                f2bu(oacc[n][ii] * inv);
    }
}

// ---------------------------------------------------------------------------
// In-place row LayerNorm over last dim (1024), eps=1e-5.
// ---------------------------------------------------------------------------
__launch_bounds__(256)
__global__ void ln_kernel(float* __restrict__ io, const float* __restrict__ gamma,
                          const float* __restrict__ beta) {
    __shared__ float wsum[4], wsum2[4];
    const int row = blockIdx.x;
    const int t = threadIdx.x;
    f4 x = *(const f4*)&io[(size_t)row * DM_ + t * 4];
    float s  = x[0] + x[1] + x[2] + x[3];
    float s2 = x[0]*x[0] + x[1]*x[1] + x[2]*x[2] + x[3]*x[3];
#pragma unroll
    for (int o = 32; o > 0; o >>= 1) {
        s  += __shfl_down(s, o);
        s2 += __shfl_down(s2, o);
    }
    if ((t & 63) == 0) { wsum[t >> 6] = s; wsum2[t >> 6] = s2; }
    __syncthreads();
    s  = wsum[0]  + wsum[1]  + wsum[2]  + wsum[3];
    s2 = wsum2[0] + wsum2[1] + wsum2[2] + wsum2[3];
    const float m = s * (1.f / DM_);
    const float var = s2 * (1.f / DM_) - m * m;
    const float rstd = rsqrtf(var + 1e-5f);
    f4 g  = *(const f4*)&gamma[t * 4];
    f4 bb = *(const f4*)&beta[t * 4];
    f4 o = (x - m) * rstd * g + bb;
    *(f4*)&io[(size_t)row * DM_ + t * 4] = o;
}

// ---------------------------------------------------------------------------
// Workspace (226 MB), staged aliasing (audited, same as round 11/14/17):
//  persistent: qp[0,64) kp[64,128) kvT[128,192) vb[192,208) attnb[208,224) ksum[224,226)
//  QKV phase:  aq[0,16) ak[16,32) av[32,48) wq[48,50) wk[50,52) wv[52,54)
//              outputs qx[128,144) kx[144,160) vb[192,208)
//  om_bf at [208,208.07) (attnb slot; dead before passC writes attnb)
//  feat: reads qx/kx+om, writes qp[0,64) + kp[64,128)
//  passA: writes kvT[128,192) ; wo_bf[64,66) after passC (kp dead)
// ---------------------------------------------------------------------------
extern "C" void kernel_launch(void* const* d_in, const int* in_sizes, int n_in,
                              void* d_out, int out_size, void* d_ws, size_t ws_size,
                              hipStream_t stream) {
    const float* pre_q = (const float*)d_in[0];
    const float* pre_k = (const float*)d_in[1];
    const float* pre_v = (const float*)d_in[2];
    const float* wq    = (const float*)d_in[3];
    const float* wk    = (const float*)d_in[4];
    const float* wv    = (const float*)d_in[5];
    const float* wo    = (const float*)d_in[6];
    const float* gamma = (const float*)d_in[7];
    const float* beta  = (const float*)d_in[8];
    const float* omega = (const float*)d_in[9];
    const float* bvec  = (const float*)d_in[10];

    const size_t NEED = 226ull << 20;
    if (ws_size < NEED) return;

    char* w = (char*)d_ws;
    unsigned short* qp    = (unsigned short*)(w);
    unsigned short* kp    = (unsigned short*)(w + (64ull << 20));
    unsigned short* kvT   = (unsigned short*)(w + (128ull << 20));
    unsigned short* vb    = (unsigned short*)(w + (192ull << 20));
    unsigned short* attnb = (unsigned short*)(w + (208ull << 20));
    float*          ksum  = (float*)(w + (224ull << 20));
    // transients
    unsigned short* aq    = (unsigned short*)(w);
    unsigned short* ak    = (unsigned short*)(w + (16ull << 20));
    unsigned short* av    = (unsigned short*)(w + (32ull << 20));
    unsigned short* wq_bf = (unsigned short*)(w + (48ull << 20));
    unsigned short* wk_bf = (unsigned short*)(w + (50ull << 20));
    unsigned short* wv_bf = (unsigned short*)(w + (52ull << 20));
    unsigned short* qx    = (unsigned short*)(w + (128ull << 20));
    unsigned short* kx    = (unsigned short*)(w + (144ull << 20));
    unsigned short* om_bf = (unsigned short*)(w + (208ull << 20));
    unsigned short* wo_bf = (unsigned short*)(w + (64ull << 20));
    float*          outb  = (float*)d_out;

    const int n4_big = M_ * DM_ / 4;
    const int n4_w   = DM_ * DM_ / 4;
    const int n4_om  = R_ * D_ / 4;
    dim3 gg3(DM_ / 128, M_ / 128, 3);   // 1536 blocks
    dim3 ggo(DM_ / 128, M_ / 128);      // out-proj: 512 blocks, 128x128

    cvt_bf16_x3<<<dim3((n4_big + 255) / 256, 1, 3), 256, 0, stream>>>(
        pre_q, pre_k, pre_v, aq, ak, av, n4_big);
    cvt_bf16_x4<<<dim3((n4_w + 255) / 256, 1, 4), 256, 0, stream>>>(
        wq, wk, wv, omega, wq_bf, wk_bf, wv_bf, om_bf, n4_w, n4_om);

    gemm_mfma_b3<<<gg3, 256, 0, stream>>>(aq, ak, av, wq_bf, wk_bf, wv_bf,
                                          qx, kx, vb, M_, DM_, DM_);
    feat_mfma_b2<<<dim3(M2_ / 64, 1, 2), 256, 0, stream>>>(qx, kx, om_bf, bvec, qp, kp);

    passA_mfma<<<dim3(NC_, H_, B_), 256, 0, stream>>>(kp, vb, kvT, ksum);
    passB_chain<<<dim3(16, H_, B_), 256, 0, stream>>>(kvT, ksum);
    passC_mfma<<<dim3(NC_, H_, B_), 256, 0, stream>>>(qp, kp, vb, kvT, ksum, attnb);

    cvt_bf16<<<(n4_w + 255) / 256, 256, 0, stream>>>(wo, wo_bf, n4_w);
    gemm_out<<<ggo, 256, 0, stream>>>(attnb, wo_bf, pre_q, outb, M_, DM_, DM_);
    ln_kernel<<<M_, 256, 0, stream>>>(outb, gamma, beta);
}